// Round 10
// baseline (1429.773 us; speedup 1.0000x reference)
//
#include <hip/hip_runtime.h>
#include <hip/hip_bf16.h>
#include <math.h>

// NTM forward, fully fused: one block per batch element, T=64 steps in-kernel.
// Rev 10: skeleton 9 -> 7 barriers.
// Model (fit over rounds: 23 seg -> 2872us, 14 -> 1466, 9 -> 1270): time is
// ~linear in barrier-delimited segments; each costs ~2-5k cycles of exposed
// dependency latency at 2 waves/SIMD. Keep removing segments:
//  - Head params fused into the head-dot segment (B3 gone): Ww/Wr repacked
//    into one permuted Head[272][256] so each head vector lands on an ALIGNED
//    wave (w0=key, w1=erase, w2=add, w3=read-key, w4 lanes0-11=scalars).
//    Activations applied to the thread's own in-register dot; |k| via in-wave
//    wsum; shift softmax via in-wave __shfl. outc partials (2x128) share the
//    segment on waves 5-6; wave 7 zeroes r.
//  - r reduce via LDS atomicAdd at the butterfly tail (B9 gone).
// Everything else = round 9 (cpre on 256 CUs, full-dot GEMVs, out-store
// overlapped with next controller, hierarchical M: reg row + LDS row).

constexpr int kB  = 64;
constexpr int kT  = 64;
constexpr int kIN = 64;
constexpr int kC  = 256;
constexpr int kN  = 1024;
constexpr int kMV = 64;
constexpr int kOUT = 64;
constexpr int kHW = 198;   // write head raw dim: MV+6+2*MV
constexpr int kHR = 70;    // read head raw dim: MV+6
constexpr int kHO = 268;   // permuted head outputs (12 scalars at 256..267)
constexpr int NT  = 512;   // threads per block (8 waves)
constexpr int NW  = NT / 64;
constexpr float kEPS = 1e-8f;

// packed weight layout, offsets in elements
constexpr int kPWc   = 0;                        // WcT  [256][128]
constexpr int kPHead = kPWc + kC * 128;          // Head [272][256] @ 32768
constexpr int kPWf   = kPHead + 272 * kC;        // WfT  [64][320]  @ 102400
constexpr int kPTotal = kPWf + kOUT * (kC + kMV);  // 122880 elements
constexpr size_t kWsPack = 256 + (size_t)kPTotal * 4;            // ~492KB
constexpr int kCpreElems = kB * kT * kC;                          // 1M floats
constexpr size_t kWsFull = kWsPack + (size_t)kCpreElems * 4;      // ~4.7MB

__device__ __forceinline__ float ldf(const float* p, int i) { return p[i]; }
__device__ __forceinline__ float ldf(const __hip_bfloat16* p, int i) { return __bfloat162float(p[i]); }
__device__ __forceinline__ void stf(float* p, int i, float v) { p[i] = v; }
__device__ __forceinline__ void stf(__hip_bfloat16* p, int i, float v) { p[i] = __float2bfloat16(v); }

// Permuted head-output -> source column.  <512: Ww column; >=512: Wr col-512.
__device__ __forceinline__ int headSrc(int o) {
  if (o < 64)  return o;                    // write key
  if (o < 128) return 70 + (o - 64);        // erase
  if (o < 192) return 134 + (o - 128);      // add
  if (o < 256) return 512 + (o - 192);      // read key
  if (o < 262) return 64 + (o - 256);       // write scalars (beta,g,s0,s1,s2,gamma)
  if (o < 268) return 512 + 64 + (o - 262); // read scalars
  return -1;
}

// 8 contiguous elements -> float[8]; 16B-aligned by construction.
__device__ __forceinline__ void ld8(const __hip_bfloat16* p, float* f) {
  uint4 u = *reinterpret_cast<const uint4*>(p);
  f[0] = __uint_as_float(u.x << 16); f[1] = __uint_as_float(u.x & 0xffff0000u);
  f[2] = __uint_as_float(u.y << 16); f[3] = __uint_as_float(u.y & 0xffff0000u);
  f[4] = __uint_as_float(u.z << 16); f[5] = __uint_as_float(u.z & 0xffff0000u);
  f[6] = __uint_as_float(u.w << 16); f[7] = __uint_as_float(u.w & 0xffff0000u);
}
__device__ __forceinline__ void ld8(const float* p, float* f) {
  float4 a = reinterpret_cast<const float4*>(p)[0];
  float4 b = reinterpret_cast<const float4*>(p)[1];
  f[0] = a.x; f[1] = a.y; f[2] = a.z; f[3] = a.w;
  f[4] = b.x; f[5] = b.y; f[6] = b.z; f[7] = b.w;
}

__device__ __forceinline__ float fexp(float v) { return __expf(v); }
__device__ __forceinline__ float sigmoidf_(float v) {
  return __fdividef(1.f, 1.f + __expf(-v));
}
__device__ __forceinline__ float softplusf_(float v) {
  return v > 20.f ? v : __logf(1.f + __expf(v));
}
__device__ __forceinline__ float ftanh(float v) {
  float a = fminf(fabsf(v), 15.f);          // tanh(15) == 1 in fp32
  float e = __expf(2.f * a);
  float t = 1.f - __fdividef(2.f, e + 1.f);
  return v < 0.f ? -t : t;
}

__device__ __forceinline__ float wsum(float v) {
  v += __shfl_xor(v, 32); v += __shfl_xor(v, 16); v += __shfl_xor(v, 8);
  v += __shfl_xor(v, 4);  v += __shfl_xor(v, 2);  v += __shfl_xor(v, 1);
  return v;
}

struct alignas(16) Smem {
  // M rows 512..1023: [block b=col/4][row r][4 floats]; lane-contiguous b128.
  float M1s[16 * 512 * 4];   // 128 KB
  float partA[1280];         // [512..640) outc partials (2x64); rest spare
  float E[kN];               // unnormalized content softmax numerators
  float WP[kN];              // previous weights (for shift conv)
  float c[kC];               // controller activations
  float r[kMV];              // read vector (atomic-accumulated)
  float k[kMV], kr[kMV], e[kMV], a[kMV];
  float bcS[kC], bfS[kOUT], bhS[272];   // biases (staged once; bhS permuted)
  float red[2][NW];          // cross-wave reduction slots
  float scal[16];            // 0..6 write head (activated), 8..14 read head
};
static_assert(sizeof(Smem) <= 160 * 1024, "LDS budget");

__device__ __forceinline__ int m1idx(int blk, int row) { return (blk * 512 + row) * 4; }

// flag: 1 if buffers are bf16, 0 if fp32.  w_bias is a softmax -> sums to 1.
__global__ void detect_dtype(const void* wb, int* flag) {
  const unsigned short* u = (const unsigned short*)wb;
  int lane = threadIdx.x;
  float s = 0.f;
  for (int i = lane; i < kN; i += 64)
    s += __uint_as_float(((unsigned int)u[i]) << 16);
  s = wsum(s);
  if (lane == 0 && blockIdx.x == 0)
    *flag = (s > 0.75f && s < 1.25f) ? 1 : 0;
}

// Repack: WcT transpose, permuted Head matrix, WfT transpose.
template <typename TD, int WANT>
__global__ void repack_w(const TD* __restrict__ Wc, const TD* __restrict__ Ww,
                         const TD* __restrict__ Wr, const TD* __restrict__ Wf,
                         TD* __restrict__ pk, const int* __restrict__ flag) {
  if (*flag != WANT) return;
  for (int idx = blockIdx.x * blockDim.x + threadIdx.x; idx < kPTotal;
       idx += gridDim.x * blockDim.x) {
    TD v = (TD)0.0f;
    if (idx < kPHead) {                     // WcT[j][i] = Wc[i][j], [128][256] src
      int r = idx, j = r >> 7, i = r & 127;
      v = Wc[i * kC + j];
    } else if (idx < kPWf) {                // Head[o][i]
      int r = idx - kPHead, o = r >> 8, i = r & 255;
      int s = headSrc(o);
      if (s >= 0) v = (s < 512) ? Ww[i * kHW + s] : Wr[i * kHR + (s - 512)];
    } else {                                // WfT[j][i] = Wf[i][j], [320][64] src
      int r = idx - kPWf, j = r / 320, i = r % 320;
      v = Wf[i * kOUT + j];
    }
    pk[idx] = v;
  }
}

// cpre[b][t][j] = bc[j] + sum_{i<64} x[b][t][i] * Wc[i][j].
template <typename TD, int WANT>
__global__ void cpre_kernel(const TD* __restrict__ x, const TD* __restrict__ bc,
                            const TD* __restrict__ pk, float* __restrict__ cpre,
                            const int* __restrict__ flag) {
  if (*flag != WANT) return;
  const int bt = blockIdx.x;              // 0..B*T-1
  const int tid = threadIdx.x;            // output j
  __shared__ float xs[kIN];
  if (tid < kIN) xs[tid] = ldf(x, (size_t)bt * kIN + tid);
  __syncthreads();
  const TD* row = pk + kPWc + tid * 128;  // WcT row j, x-part cols 0..63
  float s = ldf(bc, tid);
  #pragma unroll
  for (int q = 0; q < 8; ++q) {
    float f[8]; ld8(row + 8 * q, f);
    #pragma unroll
    for (int u = 0; u < 8; ++u) s = fmaf(xs[8 * q + u], f[u], s);
  }
  cpre[(size_t)bt * kC + tid] = s;
}

// MODE: 2 = packed + cpre, 1 = packed (x-part inline), 0 = direct strided.
template <typename TD, int WANT, int MODE>
__global__ __launch_bounds__(NT, 1) void ntm_fused(
    const TD* __restrict__ x,
    const TD* __restrict__ Wc, const TD* __restrict__ bc,
    const TD* __restrict__ Wr, const TD* __restrict__ br,
    const TD* __restrict__ Ww, const TD* __restrict__ bw,
    const TD* __restrict__ Wf, const TD* __restrict__ bf,
    const TD* __restrict__ r_bias, const TD* __restrict__ w_bias,
    const TD* __restrict__ M_bias,
    const TD* __restrict__ pk, const float* __restrict__ cpre,
    TD* __restrict__ out, const int* __restrict__ flag) {
  if (*flag != WANT) return;
  __shared__ Smem sm;
  const int tid  = threadIdx.x;
  const int b    = blockIdx.x;
  const int lane = tid & 63;
  const int wid  = tid >> 6;

  // ---- one-time staging: biases (bhS permuted), r_bias
  if (tid < kC)  sm.bcS[tid] = ldf(bc, tid);
  if (tid < kOUT) sm.bfS[tid] = ldf(bf, tid);
  if (tid < kHO) {
    int s = headSrc(tid);
    sm.bhS[tid] = (s < 512) ? ldf(bw, s) : ldf(br, s - 512);
  }
  if (tid < kMV) sm.r[tid] = ldf(r_bias, tid);

  // ---- init state: reg row (tid) + LDS row (tid+512), norms, prev weights
  float M0[kMV];
  float n2_0 = 0.f, n2_1 = 0.f;
  #pragma unroll
  for (int jb = 0; jb < kMV; jb += 8) {
    float f0[8], f1[8];
    ld8(M_bias + (size_t)tid * kMV + jb, f0);
    ld8(M_bias + (size_t)(tid + NT) * kMV + jb, f1);
    #pragma unroll
    for (int u = 0; u < 8; ++u) {
      M0[jb + u] = f0[u];
      n2_0 = fmaf(f0[u], f0[u], n2_0);
      n2_1 = fmaf(f1[u], f1[u], n2_1);
    }
    *(float4*)&sm.M1s[m1idx(jb >> 2, tid)] = make_float4(f1[0], f1[1], f1[2], f1[3]);
    *(float4*)&sm.M1s[m1idx((jb >> 2) + 1, tid)] = make_float4(f1[4], f1[5], f1[6], f1[7]);
  }
  float wp0 = ldf(w_bias, tid);
  float wp1 = ldf(w_bias, tid + NT);
  __syncthreads();

  #pragma unroll 1
  for (int t = 0; t < kT; ++t) {
    // ==== SEG 1: controller full-dot (threads 0..255)  ||  out store for
    //     step t-1 (threads 256..319).  Both depend only on r_{t-1}.
    if (tid < kC) {
      float s;
      if constexpr (MODE == 2) {
        s = cpre[((size_t)b * kT + t) * kC + tid];   // bc + x-part
      } else if constexpr (MODE == 1) {
        s = sm.bcS[tid];
        const TD* xrow = x + ((size_t)b * kT + t) * kIN;
        const TD* row = pk + kPWc + tid * 128;       // x-part cols 0..63
        #pragma unroll
        for (int q = 0; q < 8; ++q) {
          float f[8], xv[8];
          ld8(row + 8 * q, f); ld8(xrow + 8 * q, xv);
          #pragma unroll
          for (int u = 0; u < 8; ++u) s = fmaf(xv[u], f[u], s);
        }
      } else {
        s = sm.bcS[tid];
        for (int i = 0; i < kIN; ++i)
          s = fmaf(ldf(x, ((size_t)b * kT + t) * kIN + i), ldf(Wc, i * kC + tid), s);
      }
      // r-part
      if constexpr (MODE >= 1) {
        const TD* row = pk + kPWc + tid * 128 + 64;  // cols 64..127 contiguous
        #pragma unroll
        for (int q = 0; q < 8; ++q) {
          float f[8]; ld8(row + 8 * q, f);
          float4 ra = *(const float4*)&sm.r[8 * q];
          float4 rb = *(const float4*)&sm.r[8 * q + 4];
          s = fmaf(ra.x, f[0], s); s = fmaf(ra.y, f[1], s);
          s = fmaf(ra.z, f[2], s); s = fmaf(ra.w, f[3], s);
          s = fmaf(rb.x, f[4], s); s = fmaf(rb.y, f[5], s);
          s = fmaf(rb.z, f[6], s); s = fmaf(rb.w, f[7], s);
        }
      } else {
        for (int i = 0; i < kMV; ++i)
          s = fmaf(sm.r[i], ldf(Wc, (kIN + i) * kC + tid), s);
      }
      sm.c[tid] = ftanh(s);
    } else if (tid < 320 && t > 0) {
      const int j = tid - 256;
      float s = sm.bfS[j] + sm.partA[512 + j] + sm.partA[576 + j];
      if constexpr (MODE >= 1) {
        const TD* row = pk + kPWf + j * (kC + kMV) + kC;  // r-part cols 256..319
        #pragma unroll
        for (int q = 0; q < 8; ++q) {
          float f[8]; ld8(row + 8 * q, f);
          float4 ra = *(const float4*)&sm.r[8 * q];
          float4 rb = *(const float4*)&sm.r[8 * q + 4];
          s = fmaf(ra.x, f[0], s); s = fmaf(ra.y, f[1], s);
          s = fmaf(ra.z, f[2], s); s = fmaf(ra.w, f[3], s);
          s = fmaf(rb.x, f[4], s); s = fmaf(rb.y, f[5], s);
          s = fmaf(rb.z, f[6], s); s = fmaf(rb.w, f[7], s);
        }
      } else {
        for (int i = 0; i < kMV; ++i)
          s = fmaf(sm.r[i], ldf(Wf, (kC + i) * kOUT + j), s);
      }
      stf(out, ((size_t)b * kT + (t - 1)) * kOUT + j, sigmoidf_(s));
    }
    __syncthreads();                                               // B1

    // ==== SEG 2: head dots + IN-REGISTER params (waves 0-4)
    //     || outc c-partials (waves 5-6, 2x128) || zero r (wave 7)
    if (tid < kHO) {
      float a0 = 0.f, a1 = 0.f, a2 = 0.f, a3 = 0.f;
      if constexpr (MODE >= 1) {
        const TD* row = pk + kPHead + tid * kC;
        #pragma unroll 8
        for (int q = 0; q < 32; ++q) {
          float f[8]; ld8(row + 8 * q, f);
          float4 ca = *(const float4*)&sm.c[8 * q];
          float4 cb = *(const float4*)&sm.c[8 * q + 4];
          a0 = fmaf(ca.x, f[0], a0); a1 = fmaf(ca.y, f[1], a1);
          a2 = fmaf(ca.z, f[2], a2); a3 = fmaf(ca.w, f[3], a3);
          a0 = fmaf(cb.x, f[4], a0); a1 = fmaf(cb.y, f[5], a1);
          a2 = fmaf(cb.z, f[6], a2); a3 = fmaf(cb.w, f[7], a3);
        }
      } else {
        int src = headSrc(tid);
        for (int i = 0; i < kC; ++i) {
          float wv = (src < 512) ? ldf(Ww, i * kHW + src)
                                 : ldf(Wr, i * kHR + (src - 512));
          a0 = fmaf(sm.c[i], wv, a0);
        }
      }
      float dot = ((a0 + a1) + (a2 + a3)) + sm.bhS[tid];
      if (wid == 0) {                       // write key + |k|
        float kv = ftanh(dot); sm.k[lane] = kv;
        float s = wsum(kv * kv);
        if (lane == 0) sm.scal[6] = sqrtf(s);
      } else if (wid == 1) {                // erase
        sm.e[lane] = sigmoidf_(dot);
      } else if (wid == 2) {                // add
        sm.a[lane] = ftanh(dot);
      } else if (wid == 3) {                // read key + |k|
        float kv = ftanh(dot); sm.kr[lane] = kv;
        float s = wsum(kv * kv);
        if (lane == 0) sm.scal[14] = sqrtf(s);
      } else {                              // wave 4, lanes 0..11: scalars
        float d2 = __shfl(dot, 2), d3 = __shfl(dot, 3), d4 = __shfl(dot, 4);
        float d8 = __shfl(dot, 8), d9 = __shfl(dot, 9), d10 = __shfl(dot, 10);
        if (lane == 0) sm.scal[0] = softplusf_(dot);          // beta_w
        if (lane == 1) sm.scal[1] = sigmoidf_(dot);           // g_w
        if (lane == 5) sm.scal[2] = 1.f + softplusf_(dot);    // gamma_w
        if (lane == 2) {                                      // s_w softmax
          float mx = fmaxf(d2, fmaxf(d3, d4));
          float e0 = fexp(d2 - mx), e1 = fexp(d3 - mx), e2 = fexp(d4 - mx);
          float dd = __fdividef(1.f, e0 + e1 + e2);
          sm.scal[3] = e0 * dd; sm.scal[4] = e1 * dd; sm.scal[5] = e2 * dd;
        }
        if (lane == 6) sm.scal[8] = softplusf_(dot);          // beta_r
        if (lane == 7) sm.scal[9] = sigmoidf_(dot);           // g_r
        if (lane == 11) sm.scal[10] = 1.f + softplusf_(dot);  // gamma_r
        if (lane == 8) {                                      // s_r softmax
          float mx = fmaxf(d8, fmaxf(d9, d10));
          float e0 = fexp(d8 - mx), e1 = fexp(d9 - mx), e2 = fexp(d10 - mx);
          float dd = __fdividef(1.f, e0 + e1 + e2);
          sm.scal[11] = e0 * dd; sm.scal[12] = e1 * dd; sm.scal[13] = e2 * dd;
        }
      }
    } else if (tid >= 320 && tid < 448) {   // outc partials: 64 outs x 2x128
      const int j = (tid - 320) & 63, po = (tid - 320) >> 6;
      float s = 0.f;
      if constexpr (MODE >= 1) {
        const TD* row = pk + kPWf + j * (kC + kMV) + po * 128;
        #pragma unroll
        for (int q = 0; q < 16; ++q) {
          float f[8]; ld8(row + 8 * q, f);
          float4 ca = *(const float4*)&sm.c[po * 128 + 8 * q];
          float4 cb = *(const float4*)&sm.c[po * 128 + 8 * q + 4];
          s = fmaf(ca.x, f[0], s); s = fmaf(ca.y, f[1], s);
          s = fmaf(ca.z, f[2], s); s = fmaf(ca.w, f[3], s);
          s = fmaf(cb.x, f[4], s); s = fmaf(cb.y, f[5], s);
          s = fmaf(cb.z, f[6], s); s = fmaf(cb.w, f[7], s);
        }
      } else {
        for (int i = 0; i < 128; ++i)
          s = fmaf(sm.c[po * 128 + i], ldf(Wf, (po * 128 + i) * kOUT + j), s);
      }
      sm.partA[512 + po * 64 + j] = s;
    } else if (tid >= 448) {                // wave 7: zero r for atomics
      sm.r[tid - 448] = 0.f;
    }
    __syncthreads();                                               // B2

    // ==== SEG 3: write-head addressing, part 1 (dots + exp + block sum)
    float ww0, ww1;
    float gW = sm.scal[1], s0W = sm.scal[3], s1W = sm.scal[4], s2W = sm.scal[5];
    float gammaW = sm.scal[2];
    float e0W, e1W, p0W, p1W;
    {
      float beta = sm.scal[0], kn = sm.scal[6];
      float d0 = 0.f, d1 = 0.f;
      #pragma unroll
      for (int bq = 0; bq < 16; ++bq) {
        float4 kv = *(const float4*)&sm.k[bq * 4];
        d0 = fmaf(M0[bq * 4],     kv.x, d0);
        d0 = fmaf(M0[bq * 4 + 1], kv.y, d0);
        d0 = fmaf(M0[bq * 4 + 2], kv.z, d0);
        d0 = fmaf(M0[bq * 4 + 3], kv.w, d0);
        float4 mv = *(const float4*)&sm.M1s[m1idx(bq, tid)];
        d1 = fmaf(mv.x, kv.x, d1); d1 = fmaf(mv.y, kv.y, d1);
        d1 = fmaf(mv.z, kv.z, d1); d1 = fmaf(mv.w, kv.w, d1);
      }
      float sim0 = fminf(beta * d0 / (sqrtf(n2_0) * kn + kEPS), 80.f);
      float sim1 = fminf(beta * d1 / (sqrtf(n2_1) * kn + kEPS), 80.f);
      e0W = fexp(sim0); e1W = fexp(sim1);
      sm.E[tid] = e0W; sm.E[tid + NT] = e1W;
      sm.WP[tid] = wp0; sm.WP[tid + NT] = wp1;
      float sv = wsum(e0W + e1W);
      if (lane == 0) sm.red[0][wid] = sv;
    }
    __syncthreads();                                               // B3

    // ==== SEG 4: write-head addressing, part 2 (norm + shift + sharpen)
    {
      float gsum = 0.f;
      #pragma unroll
      for (int i = 0; i < NW; ++i) gsum += sm.red[0][i];
      float inv = __fdividef(1.f, gsum);
      float wg0 = fmaf(gW, fmaf(e0W, inv, -wp0), wp0);
      float wg1 = fmaf(gW, fmaf(e1W, inv, -wp1), wp1);
      int np = (tid + 1) & (kN - 1), nm = (tid + kN - 1) & (kN - 1);
      float wgp = fmaf(gW, fmaf(sm.E[np], inv, -sm.WP[np]), sm.WP[np]);
      float wgm = fmaf(gW, fmaf(sm.E[nm], inv, -sm.WP[nm]), sm.WP[nm]);
      float ws0 = s0W * wgp + s1W * wg0 + s2W * wgm;
      int npb = (tid + NT + 1) & (kN - 1), nmb = (tid + NT - 1) & (kN - 1);
      float wgpb = fmaf(gW, fmaf(sm.E[npb], inv, -sm.WP[npb]), sm.WP[npb]);
      float wgmb = fmaf(gW, fmaf(sm.E[nmb], inv, -sm.WP[nmb]), sm.WP[nmb]);
      float ws1 = s0W * wgpb + s1W * wg1 + s2W * wgmb;
      p0W = fexp(gammaW * __logf(ws0 + kEPS));
      p1W = fexp(gammaW * __logf(ws1 + kEPS));
      float pv = wsum(p0W + p1W);
      if (lane == 0) sm.red[1][wid] = pv;
    }
    __syncthreads();                                               // B4
    {
      float psum = 0.f;
      #pragma unroll
      for (int i = 0; i < NW; ++i) psum += sm.red[1][i];
      float ipn = __fdividef(1.f, psum);
      ww0 = p0W * ipn; ww1 = p1W * ipn;
    }

    // ==== SEG 5: memory update (+ read dot + norms) + read-head part 1
    float wr0, wr1;
    float gR = sm.scal[9], s0R = sm.scal[11], s1R = sm.scal[12], s2R = sm.scal[13];
    float gammaR = sm.scal[10];
    float e0R, e1R, p0R, p1R;
    float dr0 = 0.f, dr1 = 0.f, nn0 = 0.f, nn1 = 0.f;
    {
      #pragma unroll
      for (int bq = 0; bq < 16; ++bq) {
        float4 ev = *(const float4*)&sm.e[bq * 4];
        float4 av = *(const float4*)&sm.a[bq * 4];
        float4 kv = *(const float4*)&sm.kr[bq * 4];
        {
          float m = fmaf(ww0, fmaf(-ev.x, M0[bq * 4], av.x), M0[bq * 4]);
          M0[bq * 4] = m; dr0 = fmaf(m, kv.x, dr0); nn0 = fmaf(m, m, nn0);
        }
        {
          float m = fmaf(ww0, fmaf(-ev.y, M0[bq * 4 + 1], av.y), M0[bq * 4 + 1]);
          M0[bq * 4 + 1] = m; dr0 = fmaf(m, kv.y, dr0); nn0 = fmaf(m, m, nn0);
        }
        {
          float m = fmaf(ww0, fmaf(-ev.z, M0[bq * 4 + 2], av.z), M0[bq * 4 + 2]);
          M0[bq * 4 + 2] = m; dr0 = fmaf(m, kv.z, dr0); nn0 = fmaf(m, m, nn0);
        }
        {
          float m = fmaf(ww0, fmaf(-ev.w, M0[bq * 4 + 3], av.w), M0[bq * 4 + 3]);
          M0[bq * 4 + 3] = m; dr0 = fmaf(m, kv.w, dr0); nn0 = fmaf(m, m, nn0);
        }
        int fi = m1idx(bq, tid);
        float4 mv = *(const float4*)&sm.M1s[fi];
        float4 nm;
        nm.x = fmaf(ww1, fmaf(-ev.x, mv.x, av.x), mv.x);
        dr1 = fmaf(nm.x, kv.x, dr1); nn1 = fmaf(nm.x, nm.x, nn1);
        nm.y = fmaf(ww1, fmaf(-ev.y, mv.y, av.y), mv.y);
        dr1 = fmaf(nm.y, kv.y, dr1); nn1 = fmaf(nm.y, nm.y, nn1);
        nm.z = fmaf(ww1, fmaf(-ev.z, mv.z, av.z), mv.z);
        dr1 = fmaf(nm.z, kv.z, dr1); nn1 = fmaf(nm.z, nm.z, nn1);
        nm.w = fmaf(ww1, fmaf(-ev.w, mv.w, av.w), mv.w);
        dr1 = fmaf(nm.w, kv.w, dr1); nn1 = fmaf(nm.w, nm.w, nn1);
        *(float4*)&sm.M1s[fi] = nm;
      }
      float beta = sm.scal[8], kn = sm.scal[14];
      float sim0 = fminf(beta * dr0 / (sqrtf(nn0) * kn + kEPS), 80.f);
      float sim1 = fminf(beta * dr1 / (sqrtf(nn1) * kn + kEPS), 80.f);
      e0R = fexp(sim0); e1R = fexp(sim1);
      sm.E[tid] = e0R; sm.E[tid + NT] = e1R;
      sm.WP[tid] = ww0; sm.WP[tid + NT] = ww1;
      float sv = wsum(e0R + e1R);
      if (lane == 0) sm.red[0][wid] = sv;
    }
    __syncthreads();                                               // B5

    // ==== SEG 6: read-head addressing, part 2
    {
      float gsum = 0.f;
      #pragma unroll
      for (int i = 0; i < NW; ++i) gsum += sm.red[0][i];
      float inv = __fdividef(1.f, gsum);
      float wg0 = fmaf(gR, fmaf(e0R, inv, -ww0), ww0);
      float wg1 = fmaf(gR, fmaf(e1R, inv, -ww1), ww1);
      int np = (tid + 1) & (kN - 1), nm = (tid + kN - 1) & (kN - 1);
      float wgp = fmaf(gR, fmaf(sm.E[np], inv, -sm.WP[np]), sm.WP[np]);
      float wgm = fmaf(gR, fmaf(sm.E[nm], inv, -sm.WP[nm]), sm.WP[nm]);
      float ws0 = s0R * wgp + s1R * wg0 + s2R * wgm;
      int npb = (tid + NT + 1) & (kN - 1), nmb = (tid + NT - 1) & (kN - 1);
      float wgpb = fmaf(gR, fmaf(sm.E[npb], inv, -sm.WP[npb]), sm.WP[npb]);
      float wgmb = fmaf(gR, fmaf(sm.E[nmb], inv, -sm.WP[nmb]), sm.WP[nmb]);
      float ws1 = s0R * wgpb + s1R * wg1 + s2R * wgmb;
      p0R = fexp(gammaR * __logf(ws0 + kEPS));
      p1R = fexp(gammaR * __logf(ws1 + kEPS));
      float pv = wsum(p0R + p1R);
      if (lane == 0) sm.red[1][wid] = pv;
    }
    __syncthreads();                                               // B6
    {
      float psum = 0.f;
      #pragma unroll
      for (int i = 0; i < NW; ++i) psum += sm.red[1][i];
      float ipn = __fdividef(1.f, psum);
      wr0 = p0R * ipn; wr1 = p1R * ipn;
    }
    wp0 = wr0; wp1 = wr1; n2_0 = nn0; n2_1 = nn1;   // carry state

    // ==== SEG 7: read vector butterfly + atomic accumulate (B9 eliminated)
    {
      float totA, totB;
      {
        float cur[16];
        const int b0 = lane & 1;
        #pragma unroll
        for (int qq = 0; qq < 8; ++qq) {
          float4 mv = *(const float4*)&sm.M1s[m1idx(qq, tid)];
          float v0 = fmaf(wr0, M0[4 * qq],     wr1 * mv.x);
          float v1 = fmaf(wr0, M0[4 * qq + 1], wr1 * mv.y);
          float keep = b0 ? v1 : v0, send = b0 ? v0 : v1;
          cur[2 * qq] = keep + __shfl_xor(send, 1);
          float v2 = fmaf(wr0, M0[4 * qq + 2], wr1 * mv.z);
          float v3 = fmaf(wr0, M0[4 * qq + 3], wr1 * mv.w);
          keep = b0 ? v3 : v2; send = b0 ? v2 : v3;
          cur[2 * qq + 1] = keep + __shfl_xor(send, 1);
        }
        #pragma unroll
        for (int st = 1; st < 5; ++st) {
          const int d = 1 << st;
          const int bb = (lane >> st) & 1;
          #pragma unroll
          for (int q = 0; q < (16 >> st); ++q) {
            float x0 = cur[2 * q], x1 = cur[2 * q + 1];
            float keep = bb ? x1 : x0, send = bb ? x0 : x1;
            cur[q] = keep + __shfl_xor(send, d);
          }
        }
        totA = cur[0] + __shfl_xor(cur[0], 32);   // col = lane&31
      }
      {
        float cur[16];
        const int b0 = lane & 1;
        #pragma unroll
        for (int qq = 0; qq < 8; ++qq) {
          float4 mv = *(const float4*)&sm.M1s[m1idx(8 + qq, tid)];
          float v0 = fmaf(wr0, M0[32 + 4 * qq],     wr1 * mv.x);
          float v1 = fmaf(wr0, M0[32 + 4 * qq + 1], wr1 * mv.y);
          float keep = b0 ? v1 : v0, send = b0 ? v0 : v1;
          cur[2 * qq] = keep + __shfl_xor(send, 1);
          float v2 = fmaf(wr0, M0[32 + 4 * qq + 2], wr1 * mv.z);
          float v3 = fmaf(wr0, M0[32 + 4 * qq + 3], wr1 * mv.w);
          keep = b0 ? v3 : v2; send = b0 ? v2 : v3;
          cur[2 * qq + 1] = keep + __shfl_xor(send, 1);
        }
        #pragma unroll
        for (int st = 1; st < 5; ++st) {
          const int d = 1 << st;
          const int bb = (lane >> st) & 1;
          #pragma unroll
          for (int q = 0; q < (16 >> st); ++q) {
            float x0 = cur[2 * q], x1 = cur[2 * q + 1];
            float keep = bb ? x1 : x0, send = bb ? x0 : x1;
            cur[q] = keep + __shfl_xor(send, d);
          }
        }
        totB = cur[0] + __shfl_xor(cur[0], 32);   // col = 32 + (lane&31)
      }
      // lane < 32 owns col=lane (pass A); lane >= 32 owns col=lane (pass B).
      float val = (lane < 32) ? totA : totB;
      atomicAdd(&sm.r[lane], val);
    }
    __syncthreads();                                               // B7
  }

  // ==== epilogue: output for t = kT-1 (outc partials + r are intact)
  if (tid >= 256 && tid < 320) {
    const int j = tid - 256;
    float s = sm.bfS[j] + sm.partA[512 + j] + sm.partA[576 + j];
    if constexpr (MODE >= 1) {
      const TD* row = pk + kPWf + j * (kC + kMV) + kC;
      #pragma unroll
      for (int q = 0; q < 8; ++q) {
        float f[8]; ld8(row + 8 * q, f);
        float4 ra = *(const float4*)&sm.r[8 * q];
        float4 rb = *(const float4*)&sm.r[8 * q + 4];
        s = fmaf(ra.x, f[0], s); s = fmaf(ra.y, f[1], s);
        s = fmaf(ra.z, f[2], s); s = fmaf(ra.w, f[3], s);
        s = fmaf(rb.x, f[4], s); s = fmaf(rb.y, f[5], s);
        s = fmaf(rb.z, f[6], s); s = fmaf(rb.w, f[7], s);
      }
    } else {
      for (int i = 0; i < kMV; ++i)
        s = fmaf(sm.r[i], ldf(Wf, (kC + i) * kOUT + j), s);
    }
    stf(out, ((size_t)b * kT + (kT - 1)) * kOUT + j, sigmoidf_(s));
  }
}

template <typename TD, int WANT, int MODE>
static void launch_variant(void* const* d_in, void* d_out, const int* flag,
                           const void* pk, const float* cpre, hipStream_t stream) {
  ntm_fused<TD, WANT, MODE><<<dim3(kB), dim3(NT), 0, stream>>>(
      (const TD*)d_in[0], (const TD*)d_in[1], (const TD*)d_in[2],
      (const TD*)d_in[3], (const TD*)d_in[4], (const TD*)d_in[5],
      (const TD*)d_in[6], (const TD*)d_in[7], (const TD*)d_in[8],
      (const TD*)d_in[9], (const TD*)d_in[10], (const TD*)d_in[11],
      (const TD*)pk, cpre, (TD*)d_out, flag);
}

extern "C" void kernel_launch(void* const* d_in, const int* in_sizes, int n_in,
                              void* d_out, int out_size, void* d_ws, size_t ws_size,
                              hipStream_t stream) {
  (void)in_sizes; (void)n_in; (void)out_size;
  int* flag = (int*)d_ws;
  detect_dtype<<<dim3(1), dim3(64), 0, stream>>>(d_in[10], flag);
  if (ws_size >= kWsPack) {
    void* pk = (void*)((char*)d_ws + 256);
    repack_w<__hip_bfloat16, 1><<<dim3(256), dim3(256), 0, stream>>>(
        (const __hip_bfloat16*)d_in[1], (const __hip_bfloat16*)d_in[5],
        (const __hip_bfloat16*)d_in[3], (const __hip_bfloat16*)d_in[7],
        (__hip_bfloat16*)pk, flag);
    repack_w<float, 0><<<dim3(256), dim3(256), 0, stream>>>(
        (const float*)d_in[1], (const float*)d_in[5],
        (const float*)d_in[3], (const float*)d_in[7],
        (float*)pk, flag);
    if (ws_size >= kWsFull) {
      float* cpre = (float*)((char*)d_ws + kWsPack);
      cpre_kernel<__hip_bfloat16, 1><<<dim3(kB * kT), dim3(kC), 0, stream>>>(
          (const __hip_bfloat16*)d_in[0], (const __hip_bfloat16*)d_in[2],
          (const __hip_bfloat16*)pk, cpre, flag);
      cpre_kernel<float, 0><<<dim3(kB * kT), dim3(kC), 0, stream>>>(
          (const float*)d_in[0], (const float*)d_in[2],
          (const float*)pk, cpre, flag);
      launch_variant<__hip_bfloat16, 1, 2>(d_in, d_out, flag, pk, cpre, stream);
      launch_variant<float, 0, 2>(d_in, d_out, flag, pk, cpre, stream);
    } else {
      launch_variant<__hip_bfloat16, 1, 1>(d_in, d_out, flag, pk, nullptr, stream);
      launch_variant<float, 0, 1>(d_in, d_out, flag, pk, nullptr, stream);
    }
  } else {
    launch_variant<__hip_bfloat16, 1, 0>(d_in, d_out, flag, nullptr, nullptr, stream);
    launch_variant<float, 0, 0>(d_in, d_out, flag, nullptr, nullptr, stream);
  }
}

// Round 11
// 1374.347 us; speedup vs baseline: 1.0403x; 1.0403x over previous
//
#include <hip/hip_runtime.h>
#include <hip/hip_bf16.h>
#include <math.h>

// NTM forward, fully fused: one block per batch element, T=64 steps in-kernel.
// Rev 11: revert to Rev 9's 9-barrier skeleton (measured best: 1268us kernel;
// Rev 10's 7-barrier pile-up regressed to 1325us), then shorten the serial
// chains INSIDE segments:
//  - butterfly folded into read-sharpen segment using UNNORMALIZED p
//    (r = ipn * sum p*M is algebraically identical); ipn applied in the final
//    reduce. Removes B8 (9 -> 8 barriers) as true overlap, not pile-up.
//  - 4-way accumulator splits for the 64-deep single-acc fma chains
//    (ctrl r-part, outc partials, out r-part) and 2-way for the M-dot:
//    ~256cy of dependent-fma serialization each on the step-critical path.
// Everything else identical to Rev 9 (cpre on 256 CUs, full-dot GEMVs,
// out-store overlapped with next controller, hierarchical M reg+LDS row).

constexpr int kB  = 64;
constexpr int kT  = 64;
constexpr int kIN = 64;
constexpr int kC  = 256;
constexpr int kN  = 1024;
constexpr int kMV = 64;
constexpr int kOUT = 64;
constexpr int kHW = 198;   // write head raw dim: MV+6+2*MV
constexpr int kHR = 70;    // read head raw dim: MV+6
constexpr int NT  = 512;   // threads per block (8 waves)
constexpr int NW  = NT / 64;
constexpr float kEPS = 1e-8f;

// packed (transposed) weight layout, offsets in elements
constexpr int kPWc = 0;                          // WcT [256][128]
constexpr int kPWw = kPWc + kC * 128;            // WwT [198][256] @ 32768
constexpr int kPWr = kPWw + kHW * kC;            // WrT [70][256]  @ 83456
constexpr int kPWf = kPWr + kHR * kC;            // WfT [64][320]  @ 101376
constexpr int kPTotal = kPWf + kOUT * (kC + kMV);  // 121856 elements
constexpr size_t kWsPack = 256 + (size_t)kPTotal * 4;            // ~487KB
constexpr int kCpreElems = kB * kT * kC;                          // 1M floats
constexpr size_t kWsFull = kWsPack + (size_t)kCpreElems * 4;      // ~4.7MB

__device__ __forceinline__ float ldf(const float* p, int i) { return p[i]; }
__device__ __forceinline__ float ldf(const __hip_bfloat16* p, int i) { return __bfloat162float(p[i]); }
__device__ __forceinline__ void stf(float* p, int i, float v) { p[i] = v; }
__device__ __forceinline__ void stf(__hip_bfloat16* p, int i, float v) { p[i] = __float2bfloat16(v); }

// 8 contiguous elements -> float[8]; 16B-aligned by construction.
__device__ __forceinline__ void ld8(const __hip_bfloat16* p, float* f) {
  uint4 u = *reinterpret_cast<const uint4*>(p);
  f[0] = __uint_as_float(u.x << 16); f[1] = __uint_as_float(u.x & 0xffff0000u);
  f[2] = __uint_as_float(u.y << 16); f[3] = __uint_as_float(u.y & 0xffff0000u);
  f[4] = __uint_as_float(u.z << 16); f[5] = __uint_as_float(u.z & 0xffff0000u);
  f[6] = __uint_as_float(u.w << 16); f[7] = __uint_as_float(u.w & 0xffff0000u);
}
__device__ __forceinline__ void ld8(const float* p, float* f) {
  float4 a = reinterpret_cast<const float4*>(p)[0];
  float4 b = reinterpret_cast<const float4*>(p)[1];
  f[0] = a.x; f[1] = a.y; f[2] = a.z; f[3] = a.w;
  f[4] = b.x; f[5] = b.y; f[6] = b.z; f[7] = b.w;
}

__device__ __forceinline__ float fexp(float v) { return __expf(v); }
__device__ __forceinline__ float sigmoidf_(float v) {
  return __fdividef(1.f, 1.f + __expf(-v));
}
__device__ __forceinline__ float softplusf_(float v) {
  return v > 20.f ? v : __logf(1.f + __expf(v));
}
__device__ __forceinline__ float ftanh(float v) {
  float a = fminf(fabsf(v), 15.f);          // tanh(15) == 1 in fp32
  float e = __expf(2.f * a);
  float t = 1.f - __fdividef(2.f, e + 1.f);
  return v < 0.f ? -t : t;
}

__device__ __forceinline__ float wsum(float v) {
  v += __shfl_xor(v, 32); v += __shfl_xor(v, 16); v += __shfl_xor(v, 8);
  v += __shfl_xor(v, 4);  v += __shfl_xor(v, 2);  v += __shfl_xor(v, 1);
  return v;
}

// 4-accumulator dot of 64 contiguous elements against an LDS vector.
template <typename TD>
__device__ __forceinline__ float dot64(const TD* row, const float* vec) {
  float a0 = 0.f, a1 = 0.f, a2 = 0.f, a3 = 0.f;
  #pragma unroll
  for (int q = 0; q < 8; ++q) {
    float f[8]; ld8(row + 8 * q, f);
    float4 va = *(const float4*)&vec[8 * q];
    float4 vb = *(const float4*)&vec[8 * q + 4];
    a0 = fmaf(va.x, f[0], a0); a1 = fmaf(va.y, f[1], a1);
    a2 = fmaf(va.z, f[2], a2); a3 = fmaf(va.w, f[3], a3);
    a0 = fmaf(vb.x, f[4], a0); a1 = fmaf(vb.y, f[5], a1);
    a2 = fmaf(vb.z, f[6], a2); a3 = fmaf(vb.w, f[7], a3);
  }
  return (a0 + a1) + (a2 + a3);
}

struct alignas(16) Smem {
  // M rows 512..1023: [block b=col/4][row r][4 floats]; lane-contiguous b128.
  float M1s[16 * 512 * 4];   // 128 KB
  float partA[1280];         // [0..268) head dots | [512..768) outc partials
                             // | [768..1280) butterfly wave partials
  float E[kN];               // unnormalized content softmax numerators
  float WP[kN];              // previous weights (for shift conv)
  float c[kC];               // controller activations
  float r[kMV];              // read vector
  float k[kMV], kr[kMV], e[kMV], a[kMV];
  float bcS[kC], bwS[kHW], brS[kHR], bfS[kOUT];   // biases (staged once)
  float red[2][NW];          // cross-wave reduction slots
  float scal[16];            // 6: |k| write, 14: |k| read
};
static_assert(sizeof(Smem) <= 160 * 1024, "LDS budget");

__device__ __forceinline__ int m1idx(int blk, int row) { return (blk * 512 + row) * 4; }

// flag: 1 if buffers are bf16, 0 if fp32.  w_bias is a softmax -> sums to 1.
__global__ void detect_dtype(const void* wb, int* flag) {
  const unsigned short* u = (const unsigned short*)wb;
  int lane = threadIdx.x;
  float s = 0.f;
  for (int i = lane; i < kN; i += 64)
    s += __uint_as_float(((unsigned int)u[i]) << 16);
  s = wsum(s);
  if (lane == 0 && blockIdx.x == 0)
    *flag = (s > 0.75f && s < 1.25f) ? 1 : 0;
}

// Transpose-repack the four weight matrices into workspace (coalesced writes).
template <typename TD, int WANT>
__global__ void repack_w(const TD* __restrict__ Wc, const TD* __restrict__ Ww,
                         const TD* __restrict__ Wr, const TD* __restrict__ Wf,
                         TD* __restrict__ pk, const int* __restrict__ flag) {
  if (*flag != WANT) return;
  for (int idx = blockIdx.x * blockDim.x + threadIdx.x; idx < kPTotal;
       idx += gridDim.x * blockDim.x) {
    TD v;
    if (idx < kPWw) {                       // WcT[j][i] = Wc[i][j], [128][256] src
      int r = idx, j = r >> 7, i = r & 127;
      v = Wc[i * kC + j];
    } else if (idx < kPWr) {                // WwT[j][i] = Ww[i][j], [256][198] src
      int r = idx - kPWw, j = r >> 8, i = r & 255;
      v = Ww[i * kHW + j];
    } else if (idx < kPWf) {                // WrT[j][i] = Wr[i][j], [256][70] src
      int r = idx - kPWr, j = r >> 8, i = r & 255;
      v = Wr[i * kHR + j];
    } else {                                // WfT[j][i] = Wf[i][j], [320][64] src
      int r = idx - kPWf, j = r / 320, i = r % 320;
      v = Wf[i * kOUT + j];
    }
    pk[idx] = v;
  }
}

// cpre[b][t][j] = bc[j] + sum_{i<64} x[b][t][i] * Wc[i][j].
template <typename TD, int WANT>
__global__ void cpre_kernel(const TD* __restrict__ x, const TD* __restrict__ bc,
                            const TD* __restrict__ pk, float* __restrict__ cpre,
                            const int* __restrict__ flag) {
  if (*flag != WANT) return;
  const int bt = blockIdx.x;              // 0..B*T-1
  const int tid = threadIdx.x;            // output j
  __shared__ float xs[kIN];
  if (tid < kIN) xs[tid] = ldf(x, (size_t)bt * kIN + tid);
  __syncthreads();
  const TD* row = pk + kPWc + tid * 128;  // WcT row j, x-part cols 0..63
  float s = ldf(bc, tid) + dot64(row, xs);
  cpre[(size_t)bt * kC + tid] = s;
}

// MODE: 2 = packed + cpre, 1 = packed (x-part inline), 0 = direct strided.
template <typename TD, int WANT, int MODE>
__global__ __launch_bounds__(NT, 1) void ntm_fused(
    const TD* __restrict__ x,
    const TD* __restrict__ Wc, const TD* __restrict__ bc,
    const TD* __restrict__ Wr, const TD* __restrict__ br,
    const TD* __restrict__ Ww, const TD* __restrict__ bw,
    const TD* __restrict__ Wf, const TD* __restrict__ bf,
    const TD* __restrict__ r_bias, const TD* __restrict__ w_bias,
    const TD* __restrict__ M_bias,
    const TD* __restrict__ pk, const float* __restrict__ cpre,
    TD* __restrict__ out, const int* __restrict__ flag) {
  if (*flag != WANT) return;
  __shared__ Smem sm;
  const int tid  = threadIdx.x;
  const int b    = blockIdx.x;
  const int lane = tid & 63;
  const int wid  = tid >> 6;

  // ---- one-time staging: biases, r_bias
  if (tid < kC)  sm.bcS[tid] = ldf(bc, tid);
  if (tid < kHW) sm.bwS[tid] = ldf(bw, tid);
  if (tid < kHR) sm.brS[tid] = ldf(br, tid);
  if (tid < kOUT) sm.bfS[tid] = ldf(bf, tid);
  if (tid < kMV) sm.r[tid] = ldf(r_bias, tid);

  // ---- init state: reg row (tid) + LDS row (tid+512), norms, prev weights
  float M0[kMV];
  float n2_0 = 0.f, n2_1 = 0.f;
  #pragma unroll
  for (int jb = 0; jb < kMV; jb += 8) {
    float f0[8], f1[8];
    ld8(M_bias + (size_t)tid * kMV + jb, f0);
    ld8(M_bias + (size_t)(tid + NT) * kMV + jb, f1);
    #pragma unroll
    for (int u = 0; u < 8; ++u) {
      M0[jb + u] = f0[u];
      n2_0 = fmaf(f0[u], f0[u], n2_0);
      n2_1 = fmaf(f1[u], f1[u], n2_1);
    }
    *(float4*)&sm.M1s[m1idx(jb >> 2, tid)] = make_float4(f1[0], f1[1], f1[2], f1[3]);
    *(float4*)&sm.M1s[m1idx((jb >> 2) + 1, tid)] = make_float4(f1[4], f1[5], f1[6], f1[7]);
  }
  float wp0 = ldf(w_bias, tid);
  float wp1 = ldf(w_bias, tid + NT);
  __syncthreads();

  #pragma unroll 1
  for (int t = 0; t < kT; ++t) {
    // ==== SEG 1: controller full-dot (threads 0..255)  ||  out store for
    //     step t-1 (threads 256..319).  Both depend only on r_{t-1}.
    if (tid < kC) {
      float s;
      if constexpr (MODE == 2) {
        s = cpre[((size_t)b * kT + t) * kC + tid];   // bc + x-part
      } else if constexpr (MODE == 1) {
        s = sm.bcS[tid];
        const TD* xrow = x + ((size_t)b * kT + t) * kIN;
        const TD* row = pk + kPWc + tid * 128;       // x-part cols 0..63
        #pragma unroll
        for (int q = 0; q < 8; ++q) {
          float f[8], xv[8];
          ld8(row + 8 * q, f); ld8(xrow + 8 * q, xv);
          #pragma unroll
          for (int u = 0; u < 8; ++u) s = fmaf(xv[u], f[u], s);
        }
      } else {
        s = sm.bcS[tid];
        for (int i = 0; i < kIN; ++i)
          s = fmaf(ldf(x, ((size_t)b * kT + t) * kIN + i), ldf(Wc, i * kC + tid), s);
      }
      // r-part (4-acc chain)
      if constexpr (MODE >= 1) {
        s += dot64(pk + kPWc + tid * 128 + 64, sm.r);
      } else {
        for (int i = 0; i < kMV; ++i)
          s = fmaf(sm.r[i], ldf(Wc, (kIN + i) * kC + tid), s);
      }
      sm.c[tid] = ftanh(s);
    } else if (tid < 320 && t > 0) {
      const int j = tid - 256;
      float s = sm.bfS[j] + sm.partA[512 + j] + sm.partA[576 + j] +
                sm.partA[640 + j] + sm.partA[704 + j];
      if constexpr (MODE >= 1) {
        s += dot64(pk + kPWf + j * (kC + kMV) + kC, sm.r);
      } else {
        for (int i = 0; i < kMV; ++i)
          s = fmaf(sm.r[i], ldf(Wf, (kC + i) * kOUT + j), s);
      }
      stf(out, ((size_t)b * kT + (t - 1)) * kOUT + j, sigmoidf_(s));
    }
    __syncthreads();                                               // B1

    // ==== SEG 2: head full-dots (threads 0..267): hw[tid] or hr[tid-198]
    if (tid < kHW + kHR) {
      float a0 = 0.f, a1 = 0.f, a2 = 0.f, a3 = 0.f;
      if constexpr (MODE >= 1) {
        const TD* row = (tid < kHW) ? (pk + kPWw + tid * kC)
                                    : (pk + kPWr + (tid - kHW) * kC);
        #pragma unroll 8
        for (int q = 0; q < 32; ++q) {
          float f[8]; ld8(row + 8 * q, f);
          float4 ca = *(const float4*)&sm.c[8 * q];
          float4 cb = *(const float4*)&sm.c[8 * q + 4];
          a0 = fmaf(ca.x, f[0], a0); a1 = fmaf(ca.y, f[1], a1);
          a2 = fmaf(ca.z, f[2], a2); a3 = fmaf(ca.w, f[3], a3);
          a0 = fmaf(cb.x, f[4], a0); a1 = fmaf(cb.y, f[5], a1);
          a2 = fmaf(cb.z, f[6], a2); a3 = fmaf(cb.w, f[7], a3);
        }
      } else {
        for (int i = 0; i < kC; ++i) {
          float wv = (tid < kHW) ? ldf(Ww, i * kHW + tid)
                                 : ldf(Wr, i * kHR + (tid - kHW));
          a0 = fmaf(sm.c[i], wv, a0);
        }
      }
      sm.partA[tid] = (a0 + a1) + (a2 + a3);
    }
    __syncthreads();                                               // B2

    // ==== SEG 3: head vector params (waves 0..3)  ||  out c-part partials
    //     (threads 256..511: 64 outs x 4 partials of 64 c-inputs)
    if (wid == 0) {                       // write key + |k|
      float kv = ftanh(sm.partA[lane] + sm.bwS[lane]);
      sm.k[lane] = kv;
      float s = wsum(kv * kv);
      if (lane == 0) sm.scal[6] = sqrtf(s);
    } else if (wid == 1) {                // erase
      sm.e[lane] = sigmoidf_(sm.partA[70 + lane] + sm.bwS[70 + lane]);
    } else if (wid == 2) {                // add
      sm.a[lane] = ftanh(sm.partA[134 + lane] + sm.bwS[134 + lane]);
    } else if (wid == 3) {                // read key + |k|
      float kv = ftanh(sm.partA[kHW + lane] + sm.brS[lane]);
      sm.kr[lane] = kv;
      float s = wsum(kv * kv);
      if (lane == 0) sm.scal[14] = sqrtf(s);
    } else {                              // threads 256..511: outc partials
      const int j = (tid - 256) & 63, po = (tid - 256) >> 6;
      float s;
      if constexpr (MODE >= 1) {
        s = dot64(pk + kPWf + j * (kC + kMV) + po * 64, &sm.c[po * 64]);
      } else {
        s = 0.f;
        for (int i = 0; i < 64; ++i)
          s = fmaf(sm.c[po * 64 + i], ldf(Wf, (po * 64 + i) * kOUT + j), s);
      }
      sm.partA[512 + po * 64 + j] = s;
    }
    __syncthreads();                                               // B3

    // ==== SEG 4: write-head addressing, part 1 (dots + exp + block sum)
    float ww0, ww1, gW, s0W, s1W, s2W, gammaW;
    float e0W, e1W, p0W, p1W;
    {
      // head scalars, redundantly per-thread (broadcast LDS reads)
      float beta = softplusf_(sm.partA[64] + sm.bwS[64]);
      gW = sigmoidf_(sm.partA[65] + sm.bwS[65]);
      gammaW = 1.f + softplusf_(sm.partA[69] + sm.bwS[69]);
      float a0 = sm.partA[66] + sm.bwS[66];
      float a1 = sm.partA[67] + sm.bwS[67];
      float a2 = sm.partA[68] + sm.bwS[68];
      float mx = fmaxf(a0, fmaxf(a1, a2));
      float ex0 = fexp(a0 - mx), ex1 = fexp(a1 - mx), ex2 = fexp(a2 - mx);
      float dd = __fdividef(1.f, ex0 + ex1 + ex2);
      s0W = ex0 * dd; s1W = ex1 * dd; s2W = ex2 * dd;
      float kn = sm.scal[6];
      float d0a = 0.f, d0b = 0.f, d1a = 0.f, d1b = 0.f;
      #pragma unroll
      for (int bq = 0; bq < 16; ++bq) {
        float4 kv = *(const float4*)&sm.k[bq * 4];
        d0a = fmaf(M0[bq * 4],     kv.x, d0a);
        d0b = fmaf(M0[bq * 4 + 1], kv.y, d0b);
        d0a = fmaf(M0[bq * 4 + 2], kv.z, d0a);
        d0b = fmaf(M0[bq * 4 + 3], kv.w, d0b);
        float4 mv = *(const float4*)&sm.M1s[m1idx(bq, tid)];
        d1a = fmaf(mv.x, kv.x, d1a); d1b = fmaf(mv.y, kv.y, d1b);
        d1a = fmaf(mv.z, kv.z, d1a); d1b = fmaf(mv.w, kv.w, d1b);
      }
      float d0 = d0a + d0b, d1 = d1a + d1b;
      float sim0 = fminf(beta * d0 / (sqrtf(n2_0) * kn + kEPS), 80.f);
      float sim1 = fminf(beta * d1 / (sqrtf(n2_1) * kn + kEPS), 80.f);
      e0W = fexp(sim0); e1W = fexp(sim1);
      sm.E[tid] = e0W; sm.E[tid + NT] = e1W;
      sm.WP[tid] = wp0; sm.WP[tid + NT] = wp1;
      float sv = wsum(e0W + e1W);
      if (lane == 0) sm.red[0][wid] = sv;
    }
    __syncthreads();                                               // B4

    // ==== SEG 5: write-head addressing, part 2 (norm + shift + sharpen)
    {
      float gsum = 0.f;
      #pragma unroll
      for (int i = 0; i < NW; ++i) gsum += sm.red[0][i];
      float inv = __fdividef(1.f, gsum);
      float wg0 = fmaf(gW, fmaf(e0W, inv, -wp0), wp0);
      float wg1 = fmaf(gW, fmaf(e1W, inv, -wp1), wp1);
      int np = (tid + 1) & (kN - 1), nm = (tid + kN - 1) & (kN - 1);
      float wgp = fmaf(gW, fmaf(sm.E[np], inv, -sm.WP[np]), sm.WP[np]);
      float wgm = fmaf(gW, fmaf(sm.E[nm], inv, -sm.WP[nm]), sm.WP[nm]);
      float ws0 = s0W * wgp + s1W * wg0 + s2W * wgm;
      int npb = (tid + NT + 1) & (kN - 1), nmb = (tid + NT - 1) & (kN - 1);
      float wgpb = fmaf(gW, fmaf(sm.E[npb], inv, -sm.WP[npb]), sm.WP[npb]);
      float wgmb = fmaf(gW, fmaf(sm.E[nmb], inv, -sm.WP[nmb]), sm.WP[nmb]);
      float ws1 = s0W * wgpb + s1W * wg1 + s2W * wgmb;
      p0W = fexp(gammaW * __logf(ws0 + kEPS));
      p1W = fexp(gammaW * __logf(ws1 + kEPS));
      float pv = wsum(p0W + p1W);
      if (lane == 0) sm.red[1][wid] = pv;
    }
    __syncthreads();                                               // B5
    {
      float psum = 0.f;
      #pragma unroll
      for (int i = 0; i < NW; ++i) psum += sm.red[1][i];
      float ipn = __fdividef(1.f, psum);
      ww0 = p0W * ipn; ww1 = p1W * ipn;
    }

    // ==== SEG 6: memory update (+ read dot + norms) + read-head part 1
    float gR, s0R, s1R, s2R, gammaR;
    float e0R, e1R, p0R, p1R;
    float dr0 = 0.f, dr1 = 0.f, nn0 = 0.f, nn1 = 0.f;
    {
      #pragma unroll
      for (int bq = 0; bq < 16; ++bq) {
        float4 ev = *(const float4*)&sm.e[bq * 4];
        float4 av = *(const float4*)&sm.a[bq * 4];
        float4 kv = *(const float4*)&sm.kr[bq * 4];
        {
          float m = fmaf(ww0, fmaf(-ev.x, M0[bq * 4], av.x), M0[bq * 4]);
          M0[bq * 4] = m; dr0 = fmaf(m, kv.x, dr0); nn0 = fmaf(m, m, nn0);
        }
        {
          float m = fmaf(ww0, fmaf(-ev.y, M0[bq * 4 + 1], av.y), M0[bq * 4 + 1]);
          M0[bq * 4 + 1] = m; dr0 = fmaf(m, kv.y, dr0); nn0 = fmaf(m, m, nn0);
        }
        {
          float m = fmaf(ww0, fmaf(-ev.z, M0[bq * 4 + 2], av.z), M0[bq * 4 + 2]);
          M0[bq * 4 + 2] = m; dr0 = fmaf(m, kv.z, dr0); nn0 = fmaf(m, m, nn0);
        }
        {
          float m = fmaf(ww0, fmaf(-ev.w, M0[bq * 4 + 3], av.w), M0[bq * 4 + 3]);
          M0[bq * 4 + 3] = m; dr0 = fmaf(m, kv.w, dr0); nn0 = fmaf(m, m, nn0);
        }
        int fi = m1idx(bq, tid);
        float4 mv = *(const float4*)&sm.M1s[fi];
        float4 nm;
        nm.x = fmaf(ww1, fmaf(-ev.x, mv.x, av.x), mv.x);
        dr1 = fmaf(nm.x, kv.x, dr1); nn1 = fmaf(nm.x, nm.x, nn1);
        nm.y = fmaf(ww1, fmaf(-ev.y, mv.y, av.y), mv.y);
        dr1 = fmaf(nm.y, kv.y, dr1); nn1 = fmaf(nm.y, nm.y, nn1);
        nm.z = fmaf(ww1, fmaf(-ev.z, mv.z, av.z), mv.z);
        dr1 = fmaf(nm.z, kv.z, dr1); nn1 = fmaf(nm.z, nm.z, nn1);
        nm.w = fmaf(ww1, fmaf(-ev.w, mv.w, av.w), mv.w);
        dr1 = fmaf(nm.w, kv.w, dr1); nn1 = fmaf(nm.w, nm.w, nn1);
        *(float4*)&sm.M1s[fi] = nm;
      }
      // read-head scalars, redundant per-thread
      float beta = softplusf_(sm.partA[kHW + 64] + sm.brS[64]);
      gR = sigmoidf_(sm.partA[kHW + 65] + sm.brS[65]);
      gammaR = 1.f + softplusf_(sm.partA[kHW + 69] + sm.brS[69]);
      float a0 = sm.partA[kHW + 66] + sm.brS[66];
      float a1 = sm.partA[kHW + 67] + sm.brS[67];
      float a2 = sm.partA[kHW + 68] + sm.brS[68];
      float mx = fmaxf(a0, fmaxf(a1, a2));
      float ex0 = fexp(a0 - mx), ex1 = fexp(a1 - mx), ex2 = fexp(a2 - mx);
      float dd = __fdividef(1.f, ex0 + ex1 + ex2);
      s0R = ex0 * dd; s1R = ex1 * dd; s2R = ex2 * dd;
      float kn = sm.scal[14];
      float sim0 = fminf(beta * dr0 / (sqrtf(nn0) * kn + kEPS), 80.f);
      float sim1 = fminf(beta * dr1 / (sqrtf(nn1) * kn + kEPS), 80.f);
      e0R = fexp(sim0); e1R = fexp(sim1);
      sm.E[tid] = e0R; sm.E[tid + NT] = e1R;
      sm.WP[tid] = ww0; sm.WP[tid + NT] = ww1;
      float sv = wsum(e0R + e1R);
      if (lane == 0) sm.red[0][wid] = sv;
    }
    __syncthreads();                                               // B6

    // ==== SEG 7: read-head part 2 (norm + shift + sharpen)
    //      + butterfly on UNNORMALIZED p (ipn applied in SEG 8)
    {
      float gsum = 0.f;
      #pragma unroll
      for (int i = 0; i < NW; ++i) gsum += sm.red[0][i];
      float inv = __fdividef(1.f, gsum);
      float wg0 = fmaf(gR, fmaf(e0R, inv, -ww0), ww0);
      float wg1 = fmaf(gR, fmaf(e1R, inv, -ww1), ww1);
      int np = (tid + 1) & (kN - 1), nm = (tid + kN - 1) & (kN - 1);
      float wgp = fmaf(gR, fmaf(sm.E[np], inv, -sm.WP[np]), sm.WP[np]);
      float wgm = fmaf(gR, fmaf(sm.E[nm], inv, -sm.WP[nm]), sm.WP[nm]);
      float ws0 = s0R * wgp + s1R * wg0 + s2R * wgm;
      int npb = (tid + NT + 1) & (kN - 1), nmb = (tid + NT - 1) & (kN - 1);
      float wgpb = fmaf(gR, fmaf(sm.E[npb], inv, -sm.WP[npb]), sm.WP[npb]);
      float wgmb = fmaf(gR, fmaf(sm.E[nmb], inv, -sm.WP[nmb]), sm.WP[nmb]);
      float ws1 = s0R * wgpb + s1R * wg1 + s2R * wgmb;
      p0R = fexp(gammaR * __logf(ws0 + kEPS));
      p1R = fexp(gammaR * __logf(ws1 + kEPS));
      float pv = wsum(p0R + p1R);
      if (lane == 0) sm.red[1][wid] = pv;
      // butterfly pass A: columns 0..31, weights p0R/p1R (unnormalized)
      {
        float cur[16];
        const int b0 = lane & 1;
        #pragma unroll
        for (int qq = 0; qq < 8; ++qq) {
          float4 mv = *(const float4*)&sm.M1s[m1idx(qq, tid)];
          float v0 = fmaf(p0R, M0[4 * qq],     p1R * mv.x);
          float v1 = fmaf(p0R, M0[4 * qq + 1], p1R * mv.y);
          float keep = b0 ? v1 : v0, send = b0 ? v0 : v1;
          cur[2 * qq] = keep + __shfl_xor(send, 1);
          float v2 = fmaf(p0R, M0[4 * qq + 2], p1R * mv.z);
          float v3 = fmaf(p0R, M0[4 * qq + 3], p1R * mv.w);
          keep = b0 ? v3 : v2; send = b0 ? v2 : v3;
          cur[2 * qq + 1] = keep + __shfl_xor(send, 1);
        }
        #pragma unroll
        for (int st = 1; st < 5; ++st) {
          const int d = 1 << st;
          const int bb = (lane >> st) & 1;
          #pragma unroll
          for (int q = 0; q < (16 >> st); ++q) {
            float x0 = cur[2 * q], x1 = cur[2 * q + 1];
            float keep = bb ? x1 : x0, send = bb ? x0 : x1;
            cur[q] = keep + __shfl_xor(send, d);
          }
        }
        float tot = cur[0] + __shfl_xor(cur[0], 32);
        if (lane < 32) sm.partA[768 + wid * 64 + lane] = tot;
      }
      // butterfly pass B: columns 32..63
      {
        float cur[16];
        const int b0 = lane & 1;
        #pragma unroll
        for (int qq = 0; qq < 8; ++qq) {
          float4 mv = *(const float4*)&sm.M1s[m1idx(8 + qq, tid)];
          float v0 = fmaf(p0R, M0[32 + 4 * qq],     p1R * mv.x);
          float v1 = fmaf(p0R, M0[32 + 4 * qq + 1], p1R * mv.y);
          float keep = b0 ? v1 : v0, send = b0 ? v0 : v1;
          cur[2 * qq] = keep + __shfl_xor(send, 1);
          float v2 = fmaf(p0R, M0[32 + 4 * qq + 2], p1R * mv.z);
          float v3 = fmaf(p0R, M0[32 + 4 * qq + 3], p1R * mv.w);
          keep = b0 ? v3 : v2; send = b0 ? v2 : v3;
          cur[2 * qq + 1] = keep + __shfl_xor(send, 1);
        }
        #pragma unroll
        for (int st = 1; st < 5; ++st) {
          const int d = 1 << st;
          const int bb = (lane >> st) & 1;
          #pragma unroll
          for (int q = 0; q < (16 >> st); ++q) {
            float x0 = cur[2 * q], x1 = cur[2 * q + 1];
            float keep = bb ? x1 : x0, send = bb ? x0 : x1;
            cur[q] = keep + __shfl_xor(send, d);
          }
        }
        float tot = cur[0] + __shfl_xor(cur[0], 32);
        if (lane < 32) sm.partA[768 + wid * 64 + 32 + lane] = tot;
      }
    }
    __syncthreads();                                               // B7

    // ==== SEG 8: psum -> ipn; carry state; r reduce with ipn scaling
    {
      float psum = 0.f;
      #pragma unroll
      for (int i = 0; i < NW; ++i) psum += sm.red[1][i];
      float ipn = __fdividef(1.f, psum);
      wp0 = p0R * ipn; wp1 = p1R * ipn;      // carry normalized read weights
      n2_0 = nn0; n2_1 = nn1;
      if (tid < kMV) {
        float s = sm.partA[768 + tid];
        #pragma unroll
        for (int w = 1; w < NW; ++w) s += sm.partA[768 + w * 64 + tid];
        sm.r[tid] = s * ipn;
      }
    }
    __syncthreads();                                               // B8
  }

  // ==== epilogue: output for t = kT-1 (outc partials + r are intact)
  if (tid >= 256 && tid < 320) {
    const int j = tid - 256;
    float s = sm.bfS[j] + sm.partA[512 + j] + sm.partA[576 + j] +
              sm.partA[640 + j] + sm.partA[704 + j];
    if constexpr (MODE >= 1) {
      s += dot64(pk + kPWf + j * (kC + kMV) + kC, sm.r);
    } else {
      for (int i = 0; i < kMV; ++i)
        s = fmaf(sm.r[i], ldf(Wf, (kC + i) * kOUT + j), s);
    }
    stf(out, ((size_t)b * kT + (kT - 1)) * kOUT + j, sigmoidf_(s));
  }
}

template <typename TD, int WANT, int MODE>
static void launch_variant(void* const* d_in, void* d_out, const int* flag,
                           const void* pk, const float* cpre, hipStream_t stream) {
  ntm_fused<TD, WANT, MODE><<<dim3(kB), dim3(NT), 0, stream>>>(
      (const TD*)d_in[0], (const TD*)d_in[1], (const TD*)d_in[2],
      (const TD*)d_in[3], (const TD*)d_in[4], (const TD*)d_in[5],
      (const TD*)d_in[6], (const TD*)d_in[7], (const TD*)d_in[8],
      (const TD*)d_in[9], (const TD*)d_in[10], (const TD*)d_in[11],
      (const TD*)pk, cpre, (TD*)d_out, flag);
}

extern "C" void kernel_launch(void* const* d_in, const int* in_sizes, int n_in,
                              void* d_out, int out_size, void* d_ws, size_t ws_size,
                              hipStream_t stream) {
  (void)in_sizes; (void)n_in; (void)out_size;
  int* flag = (int*)d_ws;
  detect_dtype<<<dim3(1), dim3(64), 0, stream>>>(d_in[10], flag);
  if (ws_size >= kWsPack) {
    void* pk = (void*)((char*)d_ws + 256);
    repack_w<__hip_bfloat16, 1><<<dim3(256), dim3(256), 0, stream>>>(
        (const __hip_bfloat16*)d_in[1], (const __hip_bfloat16*)d_in[5],
        (const __hip_bfloat16*)d_in[3], (const __hip_bfloat16*)d_in[7],
        (__hip_bfloat16*)pk, flag);
    repack_w<float, 0><<<dim3(256), dim3(256), 0, stream>>>(
        (const float*)d_in[1], (const float*)d_in[5],
        (const float*)d_in[3], (const float*)d_in[7],
        (float*)pk, flag);
    if (ws_size >= kWsFull) {
      float* cpre = (float*)((char*)d_ws + kWsPack);
      cpre_kernel<__hip_bfloat16, 1><<<dim3(kB * kT), dim3(kC), 0, stream>>>(
          (const __hip_bfloat16*)d_in[0], (const __hip_bfloat16*)d_in[2],
          (const __hip_bfloat16*)pk, cpre, flag);
      cpre_kernel<float, 0><<<dim3(kB * kT), dim3(kC), 0, stream>>>(
          (const float*)d_in[0], (const float*)d_in[2],
          (const float*)pk, cpre, flag);
      launch_variant<__hip_bfloat16, 1, 2>(d_in, d_out, flag, pk, cpre, stream);
      launch_variant<float, 0, 2>(d_in, d_out, flag, pk, cpre, stream);
    } else {
      launch_variant<__hip_bfloat16, 1, 1>(d_in, d_out, flag, pk, nullptr, stream);
      launch_variant<float, 0, 1>(d_in, d_out, flag, pk, nullptr, stream);
    }
  } else {
    launch_variant<__hip_bfloat16, 1, 0>(d_in, d_out, flag, nullptr, nullptr, stream);
    launch_variant<float, 0, 0>(d_in, d_out, flag, nullptr, nullptr, stream);
  }
}

// Round 12
// 1010.477 us; speedup vs baseline: 1.4149x; 1.3601x over previous
//
#include <hip/hip_runtime.h>
#include <hip/hip_bf16.h>
#include <math.h>

// NTM forward, fully fused: one block per batch element, T=64 steps in-kernel.
// Rev 12: COALESCED GEMVs via si-split lanes (round-7's goal, without the
// spill). Diagnosis: each GEMV load was 16B per lane at 256-544B lane stride
// -> 64 cache lines per wave-load; ~13k line-transactions/step through the
// per-CU L1 is the largest unattacked stall term (VALUBusy(active) ~33%).
// Scheme: wave = 8 output-groups x 8 i-slices. Per load instruction, 8
// adjacent lanes read 8 adjacent 16B chunks of ONE row (128B contiguous);
// i-reduction = 3x shfl_xor(8/16/32) in-wave. Only 8 acc + 8 staged regs.
//  - SEG1 ctrl r-part: reads ORIGINAL row-major Wc rows 64..127 (waves 0-3).
//  - SEG2 head dots: HeadCat[256][320] row-major repack (Ww||Wr padded),
//    waves 0-4, full 256-deep dots, direct write to partA[o].
//  - SEG3 outc: reads ORIGINAL row-major Wf rows 0..255, waves 4-5 (i-halves,
//    2 partials). Params on waves 0-3 unchanged.
// Skeleton (8 barriers), M handling (reg row + LDS row), SEG4-8 = Rev 11.

constexpr int kB  = 64;
constexpr int kT  = 64;
constexpr int kIN = 64;
constexpr int kC  = 256;
constexpr int kN  = 1024;
constexpr int kMV = 64;
constexpr int kOUT = 64;
constexpr int kHW = 198;   // write head raw dim: MV+6+2*MV
constexpr int kHR = 70;    // read head raw dim: MV+6
constexpr int kHO = kHW + kHR;  // 268 head outputs
constexpr int kHCP = 320;  // HeadCat padded output pitch
constexpr int NT  = 512;   // threads per block (8 waves)
constexpr int NW  = NT / 64;
constexpr float kEPS = 1e-8f;

// packed weight layout, offsets in elements
constexpr int kPWc = 0;                          // WcT [256][128] (cpre x-part + MODE1)
constexpr int kPHc = kPWc + kC * 128;            // HeadCat [256][320] @ 32768
constexpr int kPWf = kPHc + kC * kHCP;           // WfT [64][320]  @ 114688
constexpr int kPTotal = kPWf + kOUT * (kC + kMV);  // 135168 elements
constexpr size_t kWsPack = 256 + (size_t)kPTotal * 4;            // ~541KB
constexpr int kCpreElems = kB * kT * kC;                          // 1M floats
constexpr size_t kWsFull = kWsPack + (size_t)kCpreElems * 4;      // ~4.7MB

__device__ __forceinline__ float ldf(const float* p, int i) { return p[i]; }
__device__ __forceinline__ float ldf(const __hip_bfloat16* p, int i) { return __bfloat162float(p[i]); }
__device__ __forceinline__ void stf(float* p, int i, float v) { p[i] = v; }
__device__ __forceinline__ void stf(__hip_bfloat16* p, int i, float v) { p[i] = __float2bfloat16(v); }

// 8 contiguous elements -> float[8]; 16B-aligned by construction.
__device__ __forceinline__ void ld8(const __hip_bfloat16* p, float* f) {
  uint4 u = *reinterpret_cast<const uint4*>(p);
  f[0] = __uint_as_float(u.x << 16); f[1] = __uint_as_float(u.x & 0xffff0000u);
  f[2] = __uint_as_float(u.y << 16); f[3] = __uint_as_float(u.y & 0xffff0000u);
  f[4] = __uint_as_float(u.z << 16); f[5] = __uint_as_float(u.z & 0xffff0000u);
  f[6] = __uint_as_float(u.w << 16); f[7] = __uint_as_float(u.w & 0xffff0000u);
}
__device__ __forceinline__ void ld8(const float* p, float* f) {
  float4 a = reinterpret_cast<const float4*>(p)[0];
  float4 b = reinterpret_cast<const float4*>(p)[1];
  f[0] = a.x; f[1] = a.y; f[2] = a.z; f[3] = a.w;
  f[4] = b.x; f[5] = b.y; f[6] = b.z; f[7] = b.w;
}

__device__ __forceinline__ float fexp(float v) { return __expf(v); }
__device__ __forceinline__ float sigmoidf_(float v) {
  return __fdividef(1.f, 1.f + __expf(-v));
}
__device__ __forceinline__ float softplusf_(float v) {
  return v > 20.f ? v : __logf(1.f + __expf(v));
}
__device__ __forceinline__ float ftanh(float v) {
  float a = fminf(fabsf(v), 15.f);          // tanh(15) == 1 in fp32
  float e = __expf(2.f * a);
  float t = 1.f - __fdividef(2.f, e + 1.f);
  return v < 0.f ? -t : t;
}

__device__ __forceinline__ float wsum(float v) {
  v += __shfl_xor(v, 32); v += __shfl_xor(v, 16); v += __shfl_xor(v, 8);
  v += __shfl_xor(v, 4);  v += __shfl_xor(v, 2);  v += __shfl_xor(v, 1);
  return v;
}

// 4-accumulator dot of 64 contiguous elements against an LDS vector.
template <typename TD>
__device__ __forceinline__ float dot64(const TD* row, const float* vec) {
  float a0 = 0.f, a1 = 0.f, a2 = 0.f, a3 = 0.f;
  #pragma unroll
  for (int q = 0; q < 8; ++q) {
    float f[8]; ld8(row + 8 * q, f);
    float4 va = *(const float4*)&vec[8 * q];
    float4 vb = *(const float4*)&vec[8 * q + 4];
    a0 = fmaf(va.x, f[0], a0); a1 = fmaf(va.y, f[1], a1);
    a2 = fmaf(va.z, f[2], a2); a3 = fmaf(va.w, f[3], a3);
    a0 = fmaf(vb.x, f[4], a0); a1 = fmaf(vb.y, f[5], a1);
    a2 = fmaf(vb.z, f[6], a2); a3 = fmaf(vb.w, f[7], a3);
  }
  return (a0 + a1) + (a2 + a3);
}

struct alignas(16) Smem {
  // M rows 512..1023: [block b=col/4][row r][4 floats]; lane-contiguous b128.
  float M1s[16 * 512 * 4];   // 128 KB
  float partA[1280];         // [0..268) head dots | [512..640) outc partials
                             // | [768..1280) butterfly wave partials
  float E[kN];               // unnormalized content softmax numerators
  float WP[kN];              // previous weights (for shift conv)
  float c[kC];               // controller activations
  float r[kMV];              // read vector
  float k[kMV], kr[kMV], e[kMV], a[kMV];
  float bcS[kC], bwS[kHW], brS[kHR], bfS[kOUT];   // biases (staged once)
  float red[2][NW];          // cross-wave reduction slots
  float scal[16];            // 6: |k| write, 14: |k| read
};
static_assert(sizeof(Smem) <= 160 * 1024, "LDS budget");

__device__ __forceinline__ int m1idx(int blk, int row) { return (blk * 512 + row) * 4; }

// flag: 1 if buffers are bf16, 0 if fp32.  w_bias is a softmax -> sums to 1.
__global__ void detect_dtype(const void* wb, int* flag) {
  const unsigned short* u = (const unsigned short*)wb;
  int lane = threadIdx.x;
  float s = 0.f;
  for (int i = lane; i < kN; i += 64)
    s += __uint_as_float(((unsigned int)u[i]) << 16);
  s = wsum(s);
  if (lane == 0 && blockIdx.x == 0)
    *flag = (s > 0.75f && s < 1.25f) ? 1 : 0;
}

// Repack: WcT transpose, HeadCat row-major pad-concat, WfT transpose.
template <typename TD, int WANT>
__global__ void repack_w(const TD* __restrict__ Wc, const TD* __restrict__ Ww,
                         const TD* __restrict__ Wr, const TD* __restrict__ Wf,
                         TD* __restrict__ pk, const int* __restrict__ flag) {
  if (*flag != WANT) return;
  for (int idx = blockIdx.x * blockDim.x + threadIdx.x; idx < kPTotal;
       idx += gridDim.x * blockDim.x) {
    TD v = (TD)0.0f;
    if (idx < kPHc) {                       // WcT[j][i] = Wc[i][j], [128][256] src
      int r = idx, j = r >> 7, i = r & 127;
      v = Wc[i * kC + j];
    } else if (idx < kPWf) {                // HeadCat[i][o] = Ww[i][o] || Wr[i][o-198]
      int r = idx - kPHc, i = r / kHCP, o = r - i * kHCP;
      if (o < kHW) v = Ww[i * kHW + o];
      else if (o < kHO) v = Wr[i * kHR + (o - kHW)];
    } else {                                // WfT[j][i] = Wf[i][j], [320][64] src
      int r = idx - kPWf, j = r / 320, i = r % 320;
      v = Wf[i * kOUT + j];
    }
    pk[idx] = v;
  }
}

// cpre[b][t][j] = bc[j] + sum_{i<64} x[b][t][i] * Wc[i][j].
template <typename TD, int WANT>
__global__ void cpre_kernel(const TD* __restrict__ x, const TD* __restrict__ bc,
                            const TD* __restrict__ pk, float* __restrict__ cpre,
                            const int* __restrict__ flag) {
  if (*flag != WANT) return;
  const int bt = blockIdx.x;              // 0..B*T-1
  const int tid = threadIdx.x;            // output j
  __shared__ float xs[kIN];
  if (tid < kIN) xs[tid] = ldf(x, (size_t)bt * kIN + tid);
  __syncthreads();
  const TD* row = pk + kPWc + tid * 128;  // WcT row j, x-part cols 0..63
  float s = ldf(bc, tid) + dot64(row, xs);
  cpre[(size_t)bt * kC + tid] = s;
}

// MODE: 2 = packed + cpre, 1 = packed (x-part inline), 0 = direct strided.
template <typename TD, int WANT, int MODE>
__global__ __launch_bounds__(NT, 1) void ntm_fused(
    const TD* __restrict__ x,
    const TD* __restrict__ Wc, const TD* __restrict__ bc,
    const TD* __restrict__ Wr, const TD* __restrict__ br,
    const TD* __restrict__ Ww, const TD* __restrict__ bw,
    const TD* __restrict__ Wf, const TD* __restrict__ bf,
    const TD* __restrict__ r_bias, const TD* __restrict__ w_bias,
    const TD* __restrict__ M_bias,
    const TD* __restrict__ pk, const float* __restrict__ cpre,
    TD* __restrict__ out, const int* __restrict__ flag) {
  if (*flag != WANT) return;
  __shared__ Smem sm;
  const int tid  = threadIdx.x;
  const int b    = blockIdx.x;
  const int lane = tid & 63;
  const int wid  = tid >> 6;

  // ---- one-time staging: biases, r_bias
  if (tid < kC)  sm.bcS[tid] = ldf(bc, tid);
  if (tid < kHW) sm.bwS[tid] = ldf(bw, tid);
  if (tid < kHR) sm.brS[tid] = ldf(br, tid);
  if (tid < kOUT) sm.bfS[tid] = ldf(bf, tid);
  if (tid < kMV) sm.r[tid] = ldf(r_bias, tid);

  // ---- init state: reg row (tid) + LDS row (tid+512), norms, prev weights
  float M0[kMV];
  float n2_0 = 0.f, n2_1 = 0.f;
  #pragma unroll
  for (int jb = 0; jb < kMV; jb += 8) {
    float f0[8], f1[8];
    ld8(M_bias + (size_t)tid * kMV + jb, f0);
    ld8(M_bias + (size_t)(tid + NT) * kMV + jb, f1);
    #pragma unroll
    for (int u = 0; u < 8; ++u) {
      M0[jb + u] = f0[u];
      n2_0 = fmaf(f0[u], f0[u], n2_0);
      n2_1 = fmaf(f1[u], f1[u], n2_1);
    }
    *(float4*)&sm.M1s[m1idx(jb >> 2, tid)] = make_float4(f1[0], f1[1], f1[2], f1[3]);
    *(float4*)&sm.M1s[m1idx((jb >> 2) + 1, tid)] = make_float4(f1[4], f1[5], f1[6], f1[7]);
  }
  float wp0 = ldf(w_bias, tid);
  float wp1 = ldf(w_bias, tid + NT);
  __syncthreads();

  #pragma unroll 1
  for (int t = 0; t < kT; ++t) {
    // ==== SEG 1: controller (coalesced si-split, waves 0..3)  ||  out store
    //     for step t-1 (threads 256..319).  Both depend only on r_{t-1}.
    if constexpr (MODE == 2) {
      if (tid < 256) {
        const int si = lane >> 3;                 // i-slice 0..7
        const int g  = (wid << 3) + (lane & 7);   // output group 0..31
        const int obase = g * 8;
        float acc[8] = {0.f, 0.f, 0.f, 0.f, 0.f, 0.f, 0.f, 0.f};
        #pragma unroll
        for (int q = 0; q < 8; ++q) {
          int i = (q << 3) + si;
          float rv = sm.r[i];
          float f[8]; ld8(Wc + (kIN + i) * kC + obase, f);  // ORIGINAL Wc row
          #pragma unroll
          for (int v = 0; v < 8; ++v) acc[v] = fmaf(rv, f[v], acc[v]);
        }
        #pragma unroll
        for (int v = 0; v < 8; ++v) {
          acc[v] += __shfl_xor(acc[v], 8);
          acc[v] += __shfl_xor(acc[v], 16);
          acc[v] += __shfl_xor(acc[v], 32);
        }
        if (si == 0) {
          const float* cp = &cpre[((size_t)b * kT + t) * kC + obase];
          float4 ca = *(const float4*)cp;
          float4 cb = *(const float4*)(cp + 4);
          sm.c[obase + 0] = ftanh(ca.x + acc[0]);
          sm.c[obase + 1] = ftanh(ca.y + acc[1]);
          sm.c[obase + 2] = ftanh(ca.z + acc[2]);
          sm.c[obase + 3] = ftanh(ca.w + acc[3]);
          sm.c[obase + 4] = ftanh(cb.x + acc[4]);
          sm.c[obase + 5] = ftanh(cb.y + acc[5]);
          sm.c[obase + 6] = ftanh(cb.z + acc[6]);
          sm.c[obase + 7] = ftanh(cb.w + acc[7]);
        }
      } else if (tid < 320 && t > 0) {
        const int j = tid - 256;
        float s = sm.bfS[j] + sm.partA[512 + j] + sm.partA[576 + j];
        s += dot64(pk + kPWf + j * (kC + kMV) + kC, sm.r);
        stf(out, ((size_t)b * kT + (t - 1)) * kOUT + j, sigmoidf_(s));
      }
    } else {
      // fallback (MODE 0/1): per-output full dot
      if (tid < kC) {
        float s;
        if constexpr (MODE == 1) {
          s = sm.bcS[tid];
          const TD* xrow = x + ((size_t)b * kT + t) * kIN;
          const TD* row = pk + kPWc + tid * 128;
          #pragma unroll
          for (int q = 0; q < 8; ++q) {
            float f[8], xv[8];
            ld8(row + 8 * q, f); ld8(xrow + 8 * q, xv);
            #pragma unroll
            for (int u = 0; u < 8; ++u) s = fmaf(xv[u], f[u], s);
          }
          s += dot64(pk + kPWc + tid * 128 + 64, sm.r);
        } else {
          s = sm.bcS[tid];
          for (int i = 0; i < kIN; ++i)
            s = fmaf(ldf(x, ((size_t)b * kT + t) * kIN + i), ldf(Wc, i * kC + tid), s);
          for (int i = 0; i < kMV; ++i)
            s = fmaf(sm.r[i], ldf(Wc, (kIN + i) * kC + tid), s);
        }
        sm.c[tid] = ftanh(s);
      } else if (tid < 320 && t > 0) {
        const int j = tid - 256;
        float s = sm.bfS[j] + sm.partA[512 + j] + sm.partA[576 + j];
        if constexpr (MODE >= 1) {
          s += dot64(pk + kPWf + j * (kC + kMV) + kC, sm.r);
        } else {
          for (int i = 0; i < kMV; ++i)
            s = fmaf(sm.r[i], ldf(Wf, (kC + i) * kOUT + j), s);
        }
        stf(out, ((size_t)b * kT + (t - 1)) * kOUT + j, sigmoidf_(s));
      }
    }
    __syncthreads();                                               // B1

    // ==== SEG 2: head full-dots (coalesced si-split over HeadCat, waves 0..4)
    if constexpr (MODE >= 1) {
      if (wid < 5) {
        const int si = lane >> 3;                 // i-slice 0..7
        const int g  = (wid << 3) + (lane & 7);   // output group 0..39
        const int obase = g * 8;                  // 0..312 (padded rows safe)
        float acc[8] = {0.f, 0.f, 0.f, 0.f, 0.f, 0.f, 0.f, 0.f};
        #pragma unroll 4
        for (int q = 0; q < 32; ++q) {
          int i = (q << 3) + si;
          float cv = sm.c[i];
          float f[8]; ld8(pk + kPHc + i * kHCP + obase, f);
          #pragma unroll
          for (int v = 0; v < 8; ++v) acc[v] = fmaf(cv, f[v], acc[v]);
        }
        #pragma unroll
        for (int v = 0; v < 8; ++v) {
          acc[v] += __shfl_xor(acc[v], 8);
          acc[v] += __shfl_xor(acc[v], 16);
          acc[v] += __shfl_xor(acc[v], 32);
        }
        if (si == 0 && obase < kHO) {
          #pragma unroll
          for (int v = 0; v < 8; ++v)
            if (obase + v < kHO) sm.partA[obase + v] = acc[v];
        }
      }
    } else {
      if (tid < kHO) {
        float a0 = 0.f;
        for (int i = 0; i < kC; ++i) {
          float wv = (tid < kHW) ? ldf(Ww, i * kHW + tid)
                                 : ldf(Wr, i * kHR + (tid - kHW));
          a0 = fmaf(sm.c[i], wv, a0);
        }
        sm.partA[tid] = a0;
      }
    }
    __syncthreads();                                               // B2

    // ==== SEG 3: head vector params (waves 0..3)  ||  outc (waves 4..5,
    //     coalesced si-split over ORIGINAL Wf, i-halves -> 2 partials)
    if (wid == 0) {                       // write key + |k|
      float kv = ftanh(sm.partA[lane] + sm.bwS[lane]);
      sm.k[lane] = kv;
      float s = wsum(kv * kv);
      if (lane == 0) sm.scal[6] = sqrtf(s);
    } else if (wid == 1) {                // erase
      sm.e[lane] = sigmoidf_(sm.partA[70 + lane] + sm.bwS[70 + lane]);
    } else if (wid == 2) {                // add
      sm.a[lane] = ftanh(sm.partA[134 + lane] + sm.bwS[134 + lane]);
    } else if (wid == 3) {                // read key + |k|
      float kv = ftanh(sm.partA[kHW + lane] + sm.brS[lane]);
      sm.kr[lane] = kv;
      float s = wsum(kv * kv);
      if (lane == 0) sm.scal[14] = sqrtf(s);
    } else if (wid == 4 || wid == 5) {    // outc partials
      const int si = lane >> 3;
      const int g  = lane & 7;            // output group 0..7
      const int obase = g * 8;
      const int ibase = (wid - 4) * 128;
      float acc[8] = {0.f, 0.f, 0.f, 0.f, 0.f, 0.f, 0.f, 0.f};
      #pragma unroll 4
      for (int q = 0; q < 16; ++q) {
        int i = ibase + (q << 3) + si;
        float cv = sm.c[i];
        float f[8]; ld8(Wf + i * kOUT + obase, f);   // ORIGINAL Wf row
        #pragma unroll
        for (int v = 0; v < 8; ++v) acc[v] = fmaf(cv, f[v], acc[v]);
      }
      #pragma unroll
      for (int v = 0; v < 8; ++v) {
        acc[v] += __shfl_xor(acc[v], 8);
        acc[v] += __shfl_xor(acc[v], 16);
        acc[v] += __shfl_xor(acc[v], 32);
      }
      if (si == 0) {
        *(float4*)&sm.partA[512 + (wid - 4) * 64 + obase] =
            make_float4(acc[0], acc[1], acc[2], acc[3]);
        *(float4*)&sm.partA[512 + (wid - 4) * 64 + obase + 4] =
            make_float4(acc[4], acc[5], acc[6], acc[7]);
      }
    }
    __syncthreads();                                               // B3

    // ==== SEG 4: write-head addressing, part 1 (dots + exp + block sum)
    float ww0, ww1, gW, s0W, s1W, s2W, gammaW;
    float e0W, e1W, p0W, p1W;
    {
      float beta = softplusf_(sm.partA[64] + sm.bwS[64]);
      gW = sigmoidf_(sm.partA[65] + sm.bwS[65]);
      gammaW = 1.f + softplusf_(sm.partA[69] + sm.bwS[69]);
      float a0 = sm.partA[66] + sm.bwS[66];
      float a1 = sm.partA[67] + sm.bwS[67];
      float a2 = sm.partA[68] + sm.bwS[68];
      float mx = fmaxf(a0, fmaxf(a1, a2));
      float ex0 = fexp(a0 - mx), ex1 = fexp(a1 - mx), ex2 = fexp(a2 - mx);
      float dd = __fdividef(1.f, ex0 + ex1 + ex2);
      s0W = ex0 * dd; s1W = ex1 * dd; s2W = ex2 * dd;
      float kn = sm.scal[6];
      float d0a = 0.f, d0b = 0.f, d1a = 0.f, d1b = 0.f;
      #pragma unroll
      for (int bq = 0; bq < 16; ++bq) {
        float4 kv = *(const float4*)&sm.k[bq * 4];
        d0a = fmaf(M0[bq * 4],     kv.x, d0a);
        d0b = fmaf(M0[bq * 4 + 1], kv.y, d0b);
        d0a = fmaf(M0[bq * 4 + 2], kv.z, d0a);
        d0b = fmaf(M0[bq * 4 + 3], kv.w, d0b);
        float4 mv = *(const float4*)&sm.M1s[m1idx(bq, tid)];
        d1a = fmaf(mv.x, kv.x, d1a); d1b = fmaf(mv.y, kv.y, d1b);
        d1a = fmaf(mv.z, kv.z, d1a); d1b = fmaf(mv.w, kv.w, d1b);
      }
      float d0 = d0a + d0b, d1 = d1a + d1b;
      float sim0 = fminf(beta * d0 / (sqrtf(n2_0) * kn + kEPS), 80.f);
      float sim1 = fminf(beta * d1 / (sqrtf(n2_1) * kn + kEPS), 80.f);
      e0W = fexp(sim0); e1W = fexp(sim1);
      sm.E[tid] = e0W; sm.E[tid + NT] = e1W;
      sm.WP[tid] = wp0; sm.WP[tid + NT] = wp1;
      float sv = wsum(e0W + e1W);
      if (lane == 0) sm.red[0][wid] = sv;
    }
    __syncthreads();                                               // B4

    // ==== SEG 5: write-head addressing, part 2 (norm + shift + sharpen)
    {
      float gsum = 0.f;
      #pragma unroll
      for (int i = 0; i < NW; ++i) gsum += sm.red[0][i];
      float inv = __fdividef(1.f, gsum);
      float wg0 = fmaf(gW, fmaf(e0W, inv, -wp0), wp0);
      float wg1 = fmaf(gW, fmaf(e1W, inv, -wp1), wp1);
      int np = (tid + 1) & (kN - 1), nm = (tid + kN - 1) & (kN - 1);
      float wgp = fmaf(gW, fmaf(sm.E[np], inv, -sm.WP[np]), sm.WP[np]);
      float wgm = fmaf(gW, fmaf(sm.E[nm], inv, -sm.WP[nm]), sm.WP[nm]);
      float ws0 = s0W * wgp + s1W * wg0 + s2W * wgm;
      int npb = (tid + NT + 1) & (kN - 1), nmb = (tid + NT - 1) & (kN - 1);
      float wgpb = fmaf(gW, fmaf(sm.E[npb], inv, -sm.WP[npb]), sm.WP[npb]);
      float wgmb = fmaf(gW, fmaf(sm.E[nmb], inv, -sm.WP[nmb]), sm.WP[nmb]);
      float ws1 = s0W * wgpb + s1W * wg1 + s2W * wgmb;
      p0W = fexp(gammaW * __logf(ws0 + kEPS));
      p1W = fexp(gammaW * __logf(ws1 + kEPS));
      float pv = wsum(p0W + p1W);
      if (lane == 0) sm.red[1][wid] = pv;
    }
    __syncthreads();                                               // B5
    {
      float psum = 0.f;
      #pragma unroll
      for (int i = 0; i < NW; ++i) psum += sm.red[1][i];
      float ipn = __fdividef(1.f, psum);
      ww0 = p0W * ipn; ww1 = p1W * ipn;
    }

    // ==== SEG 6: memory update (+ read dot + norms) + read-head part 1
    float gR, s0R, s1R, s2R, gammaR;
    float e0R, e1R, p0R, p1R;
    float dr0 = 0.f, dr1 = 0.f, nn0 = 0.f, nn1 = 0.f;
    {
      #pragma unroll
      for (int bq = 0; bq < 16; ++bq) {
        float4 ev = *(const float4*)&sm.e[bq * 4];
        float4 av = *(const float4*)&sm.a[bq * 4];
        float4 kv = *(const float4*)&sm.kr[bq * 4];
        {
          float m = fmaf(ww0, fmaf(-ev.x, M0[bq * 4], av.x), M0[bq * 4]);
          M0[bq * 4] = m; dr0 = fmaf(m, kv.x, dr0); nn0 = fmaf(m, m, nn0);
        }
        {
          float m = fmaf(ww0, fmaf(-ev.y, M0[bq * 4 + 1], av.y), M0[bq * 4 + 1]);
          M0[bq * 4 + 1] = m; dr0 = fmaf(m, kv.y, dr0); nn0 = fmaf(m, m, nn0);
        }
        {
          float m = fmaf(ww0, fmaf(-ev.z, M0[bq * 4 + 2], av.z), M0[bq * 4 + 2]);
          M0[bq * 4 + 2] = m; dr0 = fmaf(m, kv.z, dr0); nn0 = fmaf(m, m, nn0);
        }
        {
          float m = fmaf(ww0, fmaf(-ev.w, M0[bq * 4 + 3], av.w), M0[bq * 4 + 3]);
          M0[bq * 4 + 3] = m; dr0 = fmaf(m, kv.w, dr0); nn0 = fmaf(m, m, nn0);
        }
        int fi = m1idx(bq, tid);
        float4 mv = *(const float4*)&sm.M1s[fi];
        float4 nm;
        nm.x = fmaf(ww1, fmaf(-ev.x, mv.x, av.x), mv.x);
        dr1 = fmaf(nm.x, kv.x, dr1); nn1 = fmaf(nm.x, nm.x, nn1);
        nm.y = fmaf(ww1, fmaf(-ev.y, mv.y, av.y), mv.y);
        dr1 = fmaf(nm.y, kv.y, dr1); nn1 = fmaf(nm.y, nm.y, nn1);
        nm.z = fmaf(ww1, fmaf(-ev.z, mv.z, av.z), mv.z);
        dr1 = fmaf(nm.z, kv.z, dr1); nn1 = fmaf(nm.z, nm.z, nn1);
        nm.w = fmaf(ww1, fmaf(-ev.w, mv.w, av.w), mv.w);
        dr1 = fmaf(nm.w, kv.w, dr1); nn1 = fmaf(nm.w, nm.w, nn1);
        *(float4*)&sm.M1s[fi] = nm;
      }
      float beta = softplusf_(sm.partA[kHW + 64] + sm.brS[64]);
      gR = sigmoidf_(sm.partA[kHW + 65] + sm.brS[65]);
      gammaR = 1.f + softplusf_(sm.partA[kHW + 69] + sm.brS[69]);
      float a0 = sm.partA[kHW + 66] + sm.brS[66];
      float a1 = sm.partA[kHW + 67] + sm.brS[67];
      float a2 = sm.partA[kHW + 68] + sm.brS[68];
      float mx = fmaxf(a0, fmaxf(a1, a2));
      float ex0 = fexp(a0 - mx), ex1 = fexp(a1 - mx), ex2 = fexp(a2 - mx);
      float dd = __fdividef(1.f, ex0 + ex1 + ex2);
      s0R = ex0 * dd; s1R = ex1 * dd; s2R = ex2 * dd;
      float kn = sm.scal[14];
      float sim0 = fminf(beta * dr0 / (sqrtf(nn0) * kn + kEPS), 80.f);
      float sim1 = fminf(beta * dr1 / (sqrtf(nn1) * kn + kEPS), 80.f);
      e0R = fexp(sim0); e1R = fexp(sim1);
      sm.E[tid] = e0R; sm.E[tid + NT] = e1R;
      sm.WP[tid] = ww0; sm.WP[tid + NT] = ww1;
      float sv = wsum(e0R + e1R);
      if (lane == 0) sm.red[0][wid] = sv;
    }
    __syncthreads();                                               // B6

    // ==== SEG 7: read-head part 2 + butterfly on UNNORMALIZED p
    {
      float gsum = 0.f;
      #pragma unroll
      for (int i = 0; i < NW; ++i) gsum += sm.red[0][i];
      float inv = __fdividef(1.f, gsum);
      float wg0 = fmaf(gR, fmaf(e0R, inv, -ww0), ww0);
      float wg1 = fmaf(gR, fmaf(e1R, inv, -ww1), ww1);
      int np = (tid + 1) & (kN - 1), nm = (tid + kN - 1) & (kN - 1);
      float wgp = fmaf(gR, fmaf(sm.E[np], inv, -sm.WP[np]), sm.WP[np]);
      float wgm = fmaf(gR, fmaf(sm.E[nm], inv, -sm.WP[nm]), sm.WP[nm]);
      float ws0 = s0R * wgp + s1R * wg0 + s2R * wgm;
      int npb = (tid + NT + 1) & (kN - 1), nmb = (tid + NT - 1) & (kN - 1);
      float wgpb = fmaf(gR, fmaf(sm.E[npb], inv, -sm.WP[npb]), sm.WP[npb]);
      float wgmb = fmaf(gR, fmaf(sm.E[nmb], inv, -sm.WP[nmb]), sm.WP[nmb]);
      float ws1 = s0R * wgpb + s1R * wg1 + s2R * wgmb;
      p0R = fexp(gammaR * __logf(ws0 + kEPS));
      p1R = fexp(gammaR * __logf(ws1 + kEPS));
      float pv = wsum(p0R + p1R);
      if (lane == 0) sm.red[1][wid] = pv;
      // butterfly pass A: columns 0..31, weights p0R/p1R (unnormalized)
      {
        float cur[16];
        const int b0 = lane & 1;
        #pragma unroll
        for (int qq = 0; qq < 8; ++qq) {
          float4 mv = *(const float4*)&sm.M1s[m1idx(qq, tid)];
          float v0 = fmaf(p0R, M0[4 * qq],     p1R * mv.x);
          float v1 = fmaf(p0R, M0[4 * qq + 1], p1R * mv.y);
          float keep = b0 ? v1 : v0, send = b0 ? v0 : v1;
          cur[2 * qq] = keep + __shfl_xor(send, 1);
          float v2 = fmaf(p0R, M0[4 * qq + 2], p1R * mv.z);
          float v3 = fmaf(p0R, M0[4 * qq + 3], p1R * mv.w);
          keep = b0 ? v3 : v2; send = b0 ? v2 : v3;
          cur[2 * qq + 1] = keep + __shfl_xor(send, 1);
        }
        #pragma unroll
        for (int st = 1; st < 5; ++st) {
          const int d = 1 << st;
          const int bb = (lane >> st) & 1;
          #pragma unroll
          for (int q = 0; q < (16 >> st); ++q) {
            float x0 = cur[2 * q], x1 = cur[2 * q + 1];
            float keep = bb ? x1 : x0, send = bb ? x0 : x1;
            cur[q] = keep + __shfl_xor(send, d);
          }
        }
        float tot = cur[0] + __shfl_xor(cur[0], 32);
        if (lane < 32) sm.partA[768 + wid * 64 + lane] = tot;
      }
      // butterfly pass B: columns 32..63
      {
        float cur[16];
        const int b0 = lane & 1;
        #pragma unroll
        for (int qq = 0; qq < 8; ++qq) {
          float4 mv = *(const float4*)&sm.M1s[m1idx(8 + qq, tid)];
          float v0 = fmaf(p0R, M0[32 + 4 * qq],     p1R * mv.x);
          float v1 = fmaf(p0R, M0[32 + 4 * qq + 1], p1R * mv.y);
          float keep = b0 ? v1 : v0, send = b0 ? v0 : v1;
          cur[2 * qq] = keep + __shfl_xor(send, 1);
          float v2 = fmaf(p0R, M0[32 + 4 * qq + 2], p1R * mv.z);
          float v3 = fmaf(p0R, M0[32 + 4 * qq + 3], p1R * mv.w);
          keep = b0 ? v3 : v2; send = b0 ? v2 : v3;
          cur[2 * qq + 1] = keep + __shfl_xor(send, 1);
        }
        #pragma unroll
        for (int st = 1; st < 5; ++st) {
          const int d = 1 << st;
          const int bb = (lane >> st) & 1;
          #pragma unroll
          for (int q = 0; q < (16 >> st); ++q) {
            float x0 = cur[2 * q], x1 = cur[2 * q + 1];
            float keep = bb ? x1 : x0, send = bb ? x0 : x1;
            cur[q] = keep + __shfl_xor(send, d);
          }
        }
        float tot = cur[0] + __shfl_xor(cur[0], 32);
        if (lane < 32) sm.partA[768 + wid * 64 + 32 + lane] = tot;
      }
    }
    __syncthreads();                                               // B7

    // ==== SEG 8: psum -> ipn; carry state; r reduce with ipn scaling
    {
      float psum = 0.f;
      #pragma unroll
      for (int i = 0; i < NW; ++i) psum += sm.red[1][i];
      float ipn = __fdividef(1.f, psum);
      wp0 = p0R * ipn; wp1 = p1R * ipn;      // carry normalized read weights
      n2_0 = nn0; n2_1 = nn1;
      if (tid < kMV) {
        float s = sm.partA[768 + tid];
        #pragma unroll
        for (int w = 1; w < NW; ++w) s += sm.partA[768 + w * 64 + tid];
        sm.r[tid] = s * ipn;
      }
    }
    __syncthreads();                                               // B8
  }

  // ==== epilogue: output for t = kT-1 (outc partials + r are intact)
  if (tid >= 256 && tid < 320) {
    const int j = tid - 256;
    float s = sm.bfS[j] + sm.partA[512 + j] + sm.partA[576 + j];
    if constexpr (MODE >= 1) {
      s += dot64(pk + kPWf + j * (kC + kMV) + kC, sm.r);
    } else {
      for (int i = 0; i < kMV; ++i)
        s = fmaf(sm.r[i], ldf(Wf, (kC + i) * kOUT + j), s);
    }
    stf(out, ((size_t)b * kT + (kT - 1)) * kOUT + j, sigmoidf_(s));
  }
}

template <typename TD, int WANT, int MODE>
static void launch_variant(void* const* d_in, void* d_out, const int* flag,
                           const void* pk, const float* cpre, hipStream_t stream) {
  ntm_fused<TD, WANT, MODE><<<dim3(kB), dim3(NT), 0, stream>>>(
      (const TD*)d_in[0], (const TD*)d_in[1], (const TD*)d_in[2],
      (const TD*)d_in[3], (const TD*)d_in[4], (const TD*)d_in[5],
      (const TD*)d_in[6], (const TD*)d_in[7], (const TD*)d_in[8],
      (const TD*)d_in[9], (const TD*)d_in[10], (const TD*)d_in[11],
      (const TD*)pk, cpre, (TD*)d_out, flag);
}

extern "C" void kernel_launch(void* const* d_in, const int* in_sizes, int n_in,
                              void* d_out, int out_size, void* d_ws, size_t ws_size,
                              hipStream_t stream) {
  (void)in_sizes; (void)n_in; (void)out_size;
  int* flag = (int*)d_ws;
  detect_dtype<<<dim3(1), dim3(64), 0, stream>>>(d_in[10], flag);
  if (ws_size >= kWsPack) {
    void* pk = (void*)((char*)d_ws + 256);
    repack_w<__hip_bfloat16, 1><<<dim3(256), dim3(256), 0, stream>>>(
        (const __hip_bfloat16*)d_in[1], (const __hip_bfloat16*)d_in[5],
        (const __hip_bfloat16*)d_in[3], (const __hip_bfloat16*)d_in[7],
        (__hip_bfloat16*)pk, flag);
    repack_w<float, 0><<<dim3(256), dim3(256), 0, stream>>>(
        (const float*)d_in[1], (const float*)d_in[5],
        (const float*)d_in[3], (const float*)d_in[7],
        (float*)pk, flag);
    if (ws_size >= kWsFull) {
      float* cpre = (float*)((char*)d_ws + kWsPack);
      cpre_kernel<__hip_bfloat16, 1><<<dim3(kB * kT), dim3(kC), 0, stream>>>(
          (const __hip_bfloat16*)d_in[0], (const __hip_bfloat16*)d_in[2],
          (const __hip_bfloat16*)pk, cpre, flag);
      cpre_kernel<float, 0><<<dim3(kB * kT), dim3(kC), 0, stream>>>(
          (const float*)d_in[0], (const float*)d_in[2],
          (const float*)pk, cpre, flag);
      launch_variant<__hip_bfloat16, 1, 2>(d_in, d_out, flag, pk, cpre, stream);
      launch_variant<float, 0, 2>(d_in, d_out, flag, pk, cpre, stream);
    } else {
      launch_variant<__hip_bfloat16, 1, 1>(d_in, d_out, flag, pk, nullptr, stream);
      launch_variant<float, 0, 1>(d_in, d_out, flag, pk, nullptr, stream);
    }
  } else {
    launch_variant<__hip_bfloat16, 1, 0>(d_in, d_out, flag, nullptr, nullptr, stream);
    launch_variant<float, 0, 0>(d_in, d_out, flag, nullptr, nullptr, stream);
  }
}

// Round 13
// 979.735 us; speedup vs baseline: 1.4593x; 1.0314x over previous
//
#include <hip/hip_runtime.h>
#include <hip/hip_bf16.h>
#include <math.h>

// NTM forward, fully fused: one block per batch element, T=64 steps in-kernel.
// Rev 13 (on top of rev 12's coalesced si-split GEMVs, 1286 -> 908us):
//  - ALL hot weights repacked to fp32 in the workspace (WcT, HeadCat, WfT,
//    plus row-major WcR rows 64..127 and WfR for SEG1/outc which previously
//    read the original bf16 tensors). ld8(float) = 2x float4, zero unpack:
//    removes ~500 bit-ops/thread/step of bf16->f32 conversion.
//  - outc GEMV moved from SEG3 to SEG2 wave 5 (full 256-deep dot): waves 5-7
//    were idle in SEG2 and its pole is already 32 iterations, so outc hides
//    completely. SEG3 becomes params-only (short pole).
// Skeleton stays 8 barriers; M handling (reg row + LDS row), SEG4-8 = rev 12.

constexpr int kB  = 64;
constexpr int kT  = 64;
constexpr int kIN = 64;
constexpr int kC  = 256;
constexpr int kN  = 1024;
constexpr int kMV = 64;
constexpr int kOUT = 64;
constexpr int kHW = 198;   // write head raw dim: MV+6+2*MV
constexpr int kHR = 70;    // read head raw dim: MV+6
constexpr int kHO = kHW + kHR;  // 268 head outputs
constexpr int kHCP = 320;  // HeadCat padded output pitch
constexpr int NT  = 512;   // threads per block (8 waves)
constexpr int NW  = NT / 64;
constexpr float kEPS = 1e-8f;

// packed fp32 weight layout, offsets in elements
constexpr int kPWcT = 0;                           // WcT [256][128]
constexpr int kPHc  = kPWcT + kC * 128;            // HeadCat [256][320] @ 32768
constexpr int kPWfT = kPHc + kC * kHCP;            // WfT [64][320]  @ 114688
constexpr int kPWcR = kPWfT + kOUT * (kC + kMV);   // WcR [64][256]  @ 135168
constexpr int kPWfR = kPWcR + kMV * kC;            // WfR [256][64]  @ 151552
constexpr int kPTotal = kPWfR + kC * kOUT;         // 167936 elements
constexpr size_t kWsPack = 256 + (size_t)kPTotal * 4;            // ~656KB
constexpr int kCpreElems = kB * kT * kC;                          // 1M floats
constexpr size_t kWsFull = kWsPack + (size_t)kCpreElems * 4;      // ~4.9MB

__device__ __forceinline__ float ldf(const float* p, int i) { return p[i]; }
__device__ __forceinline__ float ldf(const __hip_bfloat16* p, int i) { return __bfloat162float(p[i]); }
__device__ __forceinline__ void stf(float* p, int i, float v) { p[i] = v; }
__device__ __forceinline__ void stf(__hip_bfloat16* p, int i, float v) { p[i] = __float2bfloat16(v); }

// 8 contiguous elements -> float[8]; 16B-aligned by construction.
__device__ __forceinline__ void ld8(const __hip_bfloat16* p, float* f) {
  uint4 u = *reinterpret_cast<const uint4*>(p);
  f[0] = __uint_as_float(u.x << 16); f[1] = __uint_as_float(u.x & 0xffff0000u);
  f[2] = __uint_as_float(u.y << 16); f[3] = __uint_as_float(u.y & 0xffff0000u);
  f[4] = __uint_as_float(u.z << 16); f[5] = __uint_as_float(u.z & 0xffff0000u);
  f[6] = __uint_as_float(u.w << 16); f[7] = __uint_as_float(u.w & 0xffff0000u);
}
__device__ __forceinline__ void ld8(const float* p, float* f) {
  float4 a = reinterpret_cast<const float4*>(p)[0];
  float4 b = reinterpret_cast<const float4*>(p)[1];
  f[0] = a.x; f[1] = a.y; f[2] = a.z; f[3] = a.w;
  f[4] = b.x; f[5] = b.y; f[6] = b.z; f[7] = b.w;
}

__device__ __forceinline__ float fexp(float v) { return __expf(v); }
__device__ __forceinline__ float sigmoidf_(float v) {
  return __fdividef(1.f, 1.f + __expf(-v));
}
__device__ __forceinline__ float softplusf_(float v) {
  return v > 20.f ? v : __logf(1.f + __expf(v));
}
__device__ __forceinline__ float ftanh(float v) {
  float a = fminf(fabsf(v), 15.f);          // tanh(15) == 1 in fp32
  float e = __expf(2.f * a);
  float t = 1.f - __fdividef(2.f, e + 1.f);
  return v < 0.f ? -t : t;
}

__device__ __forceinline__ float wsum(float v) {
  v += __shfl_xor(v, 32); v += __shfl_xor(v, 16); v += __shfl_xor(v, 8);
  v += __shfl_xor(v, 4);  v += __shfl_xor(v, 2);  v += __shfl_xor(v, 1);
  return v;
}

// 4-accumulator dot of 64 contiguous elements against an LDS vector.
template <typename TD>
__device__ __forceinline__ float dot64(const TD* row, const float* vec) {
  float a0 = 0.f, a1 = 0.f, a2 = 0.f, a3 = 0.f;
  #pragma unroll
  for (int q = 0; q < 8; ++q) {
    float f[8]; ld8(row + 8 * q, f);
    float4 va = *(const float4*)&vec[8 * q];
    float4 vb = *(const float4*)&vec[8 * q + 4];
    a0 = fmaf(va.x, f[0], a0); a1 = fmaf(va.y, f[1], a1);
    a2 = fmaf(va.z, f[2], a2); a3 = fmaf(va.w, f[3], a3);
    a0 = fmaf(vb.x, f[4], a0); a1 = fmaf(vb.y, f[5], a1);
    a2 = fmaf(vb.z, f[6], a2); a3 = fmaf(vb.w, f[7], a3);
  }
  return (a0 + a1) + (a2 + a3);
}

struct alignas(16) Smem {
  // M rows 512..1023: [block b=col/4][row r][4 floats]; lane-contiguous b128.
  float M1s[16 * 512 * 4];   // 128 KB
  float partA[1280];         // [0..268) head dots | [512..576) outc dots
                             // | [768..1280) butterfly wave partials
  float E[kN];               // unnormalized content softmax numerators
  float WP[kN];              // previous weights (for shift conv)
  float c[kC];               // controller activations
  float r[kMV];              // read vector
  float k[kMV], kr[kMV], e[kMV], a[kMV];
  float bcS[kC], bwS[kHW], brS[kHR], bfS[kOUT];   // biases (staged once)
  float red[2][NW];          // cross-wave reduction slots
  float scal[16];            // 6: |k| write, 14: |k| read
};
static_assert(sizeof(Smem) <= 160 * 1024, "LDS budget");

__device__ __forceinline__ int m1idx(int blk, int row) { return (blk * 512 + row) * 4; }

// flag: 1 if buffers are bf16, 0 if fp32.  w_bias is a softmax -> sums to 1.
__global__ void detect_dtype(const void* wb, int* flag) {
  const unsigned short* u = (const unsigned short*)wb;
  int lane = threadIdx.x;
  float s = 0.f;
  for (int i = lane; i < kN; i += 64)
    s += __uint_as_float(((unsigned int)u[i]) << 16);
  s = wsum(s);
  if (lane == 0 && blockIdx.x == 0)
    *flag = (s > 0.75f && s < 1.25f) ? 1 : 0;
}

// Repack everything to fp32: WcT, HeadCat, WfT, WcR (rows 64..127), WfR.
template <typename TD, int WANT>
__global__ void repack_w(const TD* __restrict__ Wc, const TD* __restrict__ Ww,
                         const TD* __restrict__ Wr, const TD* __restrict__ Wf,
                         float* __restrict__ pk, const int* __restrict__ flag) {
  if (*flag != WANT) return;
  for (int idx = blockIdx.x * blockDim.x + threadIdx.x; idx < kPTotal;
       idx += gridDim.x * blockDim.x) {
    float v = 0.0f;
    if (idx < kPHc) {                        // WcT[j][i] = Wc[i][j]
      int r = idx, j = r >> 7, i = r & 127;
      v = ldf(Wc, i * kC + j);
    } else if (idx < kPWfT) {                // HeadCat[i][o] = Ww[i][o] || Wr
      int r = idx - kPHc, i = r / kHCP, o = r - i * kHCP;
      if (o < kHW) v = ldf(Ww, i * kHW + o);
      else if (o < kHO) v = ldf(Wr, i * kHR + (o - kHW));
    } else if (idx < kPWcR) {                // WfT[j][i] = Wf[i][j]
      int r = idx - kPWfT, j = r / 320, i = r % 320;
      v = ldf(Wf, i * kOUT + j);
    } else if (idx < kPWfR) {                // WcR[i][j] = Wc[64+i][j]
      int r = idx - kPWcR, i = r >> 8, j = r & 255;
      v = ldf(Wc, (kIN + i) * kC + j);
    } else {                                 // WfR[i][j] = Wf[i][j]
      int r = idx - kPWfR, i = r >> 6, j = r & 63;
      v = ldf(Wf, i * kOUT + j);
    }
    pk[idx] = v;
  }
}

// cpre[b][t][j] = bc[j] + sum_{i<64} x[b][t][i] * Wc[i][j].
template <typename TD, int WANT>
__global__ void cpre_kernel(const TD* __restrict__ x, const TD* __restrict__ bc,
                            const float* __restrict__ pk, float* __restrict__ cpre,
                            const int* __restrict__ flag) {
  if (*flag != WANT) return;
  const int bt = blockIdx.x;              // 0..B*T-1
  const int tid = threadIdx.x;            // output j
  __shared__ float xs[kIN];
  if (tid < kIN) xs[tid] = ldf(x, (size_t)bt * kIN + tid);
  __syncthreads();
  const float* row = pk + kPWcT + tid * 128;  // WcT row j, x-part cols 0..63
  float s = ldf(bc, tid) + dot64(row, xs);
  cpre[(size_t)bt * kC + tid] = s;
}

// MODE: 2 = packed + cpre, 1 = packed (x-part inline), 0 = direct strided.
template <typename TD, int WANT, int MODE>
__global__ __launch_bounds__(NT, 1) void ntm_fused(
    const TD* __restrict__ x,
    const TD* __restrict__ Wc, const TD* __restrict__ bc,
    const TD* __restrict__ Wr, const TD* __restrict__ br,
    const TD* __restrict__ Ww, const TD* __restrict__ bw,
    const TD* __restrict__ Wf, const TD* __restrict__ bf,
    const TD* __restrict__ r_bias, const TD* __restrict__ w_bias,
    const TD* __restrict__ M_bias,
    const float* __restrict__ pk, const float* __restrict__ cpre,
    TD* __restrict__ out, const int* __restrict__ flag) {
  if (*flag != WANT) return;
  __shared__ Smem sm;
  const int tid  = threadIdx.x;
  const int b    = blockIdx.x;
  const int lane = tid & 63;
  const int wid  = tid >> 6;

  // ---- one-time staging: biases, r_bias
  if (tid < kC)  sm.bcS[tid] = ldf(bc, tid);
  if (tid < kHW) sm.bwS[tid] = ldf(bw, tid);
  if (tid < kHR) sm.brS[tid] = ldf(br, tid);
  if (tid < kOUT) sm.bfS[tid] = ldf(bf, tid);
  if (tid < kMV) sm.r[tid] = ldf(r_bias, tid);

  // ---- init state: reg row (tid) + LDS row (tid+512), norms, prev weights
  float M0[kMV];
  float n2_0 = 0.f, n2_1 = 0.f;
  #pragma unroll
  for (int jb = 0; jb < kMV; jb += 8) {
    float f0[8], f1[8];
    ld8(M_bias + (size_t)tid * kMV + jb, f0);
    ld8(M_bias + (size_t)(tid + NT) * kMV + jb, f1);
    #pragma unroll
    for (int u = 0; u < 8; ++u) {
      M0[jb + u] = f0[u];
      n2_0 = fmaf(f0[u], f0[u], n2_0);
      n2_1 = fmaf(f1[u], f1[u], n2_1);
    }
    *(float4*)&sm.M1s[m1idx(jb >> 2, tid)] = make_float4(f1[0], f1[1], f1[2], f1[3]);
    *(float4*)&sm.M1s[m1idx((jb >> 2) + 1, tid)] = make_float4(f1[4], f1[5], f1[6], f1[7]);
  }
  float wp0 = ldf(w_bias, tid);
  float wp1 = ldf(w_bias, tid + NT);
  __syncthreads();

  #pragma unroll 1
  for (int t = 0; t < kT; ++t) {
    // ==== SEG 1: controller (coalesced si-split, waves 0..3)  ||  out store
    //     for step t-1 (threads 256..319).  Both depend only on r_{t-1}.
    if constexpr (MODE == 2) {
      if (tid < 256) {
        const int si = lane >> 3;                 // i-slice 0..7
        const int g  = (wid << 3) + (lane & 7);   // output group 0..31
        const int obase = g * 8;
        float acc[8] = {0.f, 0.f, 0.f, 0.f, 0.f, 0.f, 0.f, 0.f};
        #pragma unroll
        for (int q = 0; q < 8; ++q) {
          int i = (q << 3) + si;
          float rv = sm.r[i];
          float f[8]; ld8(pk + kPWcR + i * kC + obase, f);   // fp32 WcR row
          #pragma unroll
          for (int v = 0; v < 8; ++v) acc[v] = fmaf(rv, f[v], acc[v]);
        }
        #pragma unroll
        for (int v = 0; v < 8; ++v) {
          acc[v] += __shfl_xor(acc[v], 8);
          acc[v] += __shfl_xor(acc[v], 16);
          acc[v] += __shfl_xor(acc[v], 32);
        }
        if (si == 0) {
          const float* cp = &cpre[((size_t)b * kT + t) * kC + obase];
          float4 ca = *(const float4*)cp;
          float4 cb = *(const float4*)(cp + 4);
          sm.c[obase + 0] = ftanh(ca.x + acc[0]);
          sm.c[obase + 1] = ftanh(ca.y + acc[1]);
          sm.c[obase + 2] = ftanh(ca.z + acc[2]);
          sm.c[obase + 3] = ftanh(ca.w + acc[3]);
          sm.c[obase + 4] = ftanh(cb.x + acc[4]);
          sm.c[obase + 5] = ftanh(cb.y + acc[5]);
          sm.c[obase + 6] = ftanh(cb.z + acc[6]);
          sm.c[obase + 7] = ftanh(cb.w + acc[7]);
        }
      } else if (tid < 320 && t > 0) {
        const int j = tid - 256;
        float s = sm.bfS[j] + sm.partA[512 + j];
        s += dot64(pk + kPWfT + j * (kC + kMV) + kC, sm.r);
        stf(out, ((size_t)b * kT + (t - 1)) * kOUT + j, sigmoidf_(s));
      }
    } else {
      // fallback (MODE 0/1): per-output full dot
      if (tid < kC) {
        float s;
        if constexpr (MODE == 1) {
          s = sm.bcS[tid];
          const TD* xrow = x + ((size_t)b * kT + t) * kIN;
          const float* row = pk + kPWcT + tid * 128;
          #pragma unroll
          for (int q = 0; q < 8; ++q) {
            float f[8], xv[8];
            ld8(row + 8 * q, f); ld8(xrow + 8 * q, xv);
            #pragma unroll
            for (int u = 0; u < 8; ++u) s = fmaf(xv[u], f[u], s);
          }
          s += dot64(pk + kPWcT + tid * 128 + 64, sm.r);
        } else {
          s = sm.bcS[tid];
          for (int i = 0; i < kIN; ++i)
            s = fmaf(ldf(x, ((size_t)b * kT + t) * kIN + i), ldf(Wc, i * kC + tid), s);
          for (int i = 0; i < kMV; ++i)
            s = fmaf(sm.r[i], ldf(Wc, (kIN + i) * kC + tid), s);
        }
        sm.c[tid] = ftanh(s);
      } else if (tid < 320 && t > 0) {
        const int j = tid - 256;
        float s = sm.bfS[j] + sm.partA[512 + j];
        if constexpr (MODE == 1) {
          s += dot64(pk + kPWfT + j * (kC + kMV) + kC, sm.r);
        } else {
          for (int i = 0; i < kMV; ++i)
            s = fmaf(sm.r[i], ldf(Wf, (kC + i) * kOUT + j), s);
        }
        stf(out, ((size_t)b * kT + (t - 1)) * kOUT + j, sigmoidf_(s));
      }
    }
    __syncthreads();                                               // B1

    // ==== SEG 2: head full-dots (si-split over HeadCat, waves 0..4)
    //     || outc full-dots (wave 5, si-split over WfR) || waves 6-7 idle
    if constexpr (MODE >= 1) {
      if (wid < 5) {
        const int si = lane >> 3;                 // i-slice 0..7
        const int g  = (wid << 3) + (lane & 7);   // output group 0..39
        const int obase = g * 8;                  // 0..312 (padded rows safe)
        float acc[8] = {0.f, 0.f, 0.f, 0.f, 0.f, 0.f, 0.f, 0.f};
        #pragma unroll 4
        for (int q = 0; q < 32; ++q) {
          int i = (q << 3) + si;
          float cv = sm.c[i];
          float f[8]; ld8(pk + kPHc + i * kHCP + obase, f);
          #pragma unroll
          for (int v = 0; v < 8; ++v) acc[v] = fmaf(cv, f[v], acc[v]);
        }
        #pragma unroll
        for (int v = 0; v < 8; ++v) {
          acc[v] += __shfl_xor(acc[v], 8);
          acc[v] += __shfl_xor(acc[v], 16);
          acc[v] += __shfl_xor(acc[v], 32);
        }
        if (si == 0 && obase < kHO) {
          #pragma unroll
          for (int v = 0; v < 8; ++v)
            if (obase + v < kHO) sm.partA[obase + v] = acc[v];
        }
      } else if (wid == 5) {
        const int si = lane >> 3;
        const int g  = lane & 7;                  // output group 0..7
        const int obase = g * 8;
        float acc[8] = {0.f, 0.f, 0.f, 0.f, 0.f, 0.f, 0.f, 0.f};
        #pragma unroll 4
        for (int q = 0; q < 32; ++q) {
          int i = (q << 3) + si;
          float cv = sm.c[i];
          float f[8]; ld8(pk + kPWfR + i * kOUT + obase, f);
          #pragma unroll
          for (int v = 0; v < 8; ++v) acc[v] = fmaf(cv, f[v], acc[v]);
        }
        #pragma unroll
        for (int v = 0; v < 8; ++v) {
          acc[v] += __shfl_xor(acc[v], 8);
          acc[v] += __shfl_xor(acc[v], 16);
          acc[v] += __shfl_xor(acc[v], 32);
        }
        if (si == 0) {
          *(float4*)&sm.partA[512 + obase] =
              make_float4(acc[0], acc[1], acc[2], acc[3]);
          *(float4*)&sm.partA[512 + obase + 4] =
              make_float4(acc[4], acc[5], acc[6], acc[7]);
        }
      }
    } else {
      if (tid < kHO) {
        float a0 = 0.f;
        for (int i = 0; i < kC; ++i) {
          float wv = (tid < kHW) ? ldf(Ww, i * kHW + tid)
                                 : ldf(Wr, i * kHR + (tid - kHW));
          a0 = fmaf(sm.c[i], wv, a0);
        }
        sm.partA[tid] = a0;
      } else if (wid == 5) {                // outc (strided fallback)
        const int si = lane >> 3;
        const int g  = lane & 7;
        const int obase = g * 8;
        float acc[8] = {0.f, 0.f, 0.f, 0.f, 0.f, 0.f, 0.f, 0.f};
        for (int q = 0; q < 32; ++q) {
          int i = (q << 3) + si;
          float cv = sm.c[i];
          #pragma unroll
          for (int v = 0; v < 8; ++v)
            acc[v] = fmaf(cv, ldf(Wf, i * kOUT + obase + v), acc[v]);
        }
        #pragma unroll
        for (int v = 0; v < 8; ++v) {
          acc[v] += __shfl_xor(acc[v], 8);
          acc[v] += __shfl_xor(acc[v], 16);
          acc[v] += __shfl_xor(acc[v], 32);
        }
        if (si == 0) {
          #pragma unroll
          for (int v = 0; v < 8; ++v) sm.partA[512 + obase + v] = acc[v];
        }
      }
    }
    __syncthreads();                                               // B2

    // ==== SEG 3: head vector params only (waves 0..3; short pole)
    if (wid == 0) {                       // write key + |k|
      float kv = ftanh(sm.partA[lane] + sm.bwS[lane]);
      sm.k[lane] = kv;
      float s = wsum(kv * kv);
      if (lane == 0) sm.scal[6] = sqrtf(s);
    } else if (wid == 1) {                // erase
      sm.e[lane] = sigmoidf_(sm.partA[70 + lane] + sm.bwS[70 + lane]);
    } else if (wid == 2) {                // add
      sm.a[lane] = ftanh(sm.partA[134 + lane] + sm.bwS[134 + lane]);
    } else if (wid == 3) {                // read key + |k|
      float kv = ftanh(sm.partA[kHW + lane] + sm.brS[lane]);
      sm.kr[lane] = kv;
      float s = wsum(kv * kv);
      if (lane == 0) sm.scal[14] = sqrtf(s);
    }
    __syncthreads();                                               // B3

    // ==== SEG 4: write-head addressing, part 1 (dots + exp + block sum)
    float ww0, ww1, gW, s0W, s1W, s2W, gammaW;
    float e0W, e1W, p0W, p1W;
    {
      float beta = softplusf_(sm.partA[64] + sm.bwS[64]);
      gW = sigmoidf_(sm.partA[65] + sm.bwS[65]);
      gammaW = 1.f + softplusf_(sm.partA[69] + sm.bwS[69]);
      float a0 = sm.partA[66] + sm.bwS[66];
      float a1 = sm.partA[67] + sm.bwS[67];
      float a2 = sm.partA[68] + sm.bwS[68];
      float mx = fmaxf(a0, fmaxf(a1, a2));
      float ex0 = fexp(a0 - mx), ex1 = fexp(a1 - mx), ex2 = fexp(a2 - mx);
      float dd = __fdividef(1.f, ex0 + ex1 + ex2);
      s0W = ex0 * dd; s1W = ex1 * dd; s2W = ex2 * dd;
      float kn = sm.scal[6];
      float d0a = 0.f, d0b = 0.f, d1a = 0.f, d1b = 0.f;
      #pragma unroll
      for (int bq = 0; bq < 16; ++bq) {
        float4 kv = *(const float4*)&sm.k[bq * 4];
        d0a = fmaf(M0[bq * 4],     kv.x, d0a);
        d0b = fmaf(M0[bq * 4 + 1], kv.y, d0b);
        d0a = fmaf(M0[bq * 4 + 2], kv.z, d0a);
        d0b = fmaf(M0[bq * 4 + 3], kv.w, d0b);
        float4 mv = *(const float4*)&sm.M1s[m1idx(bq, tid)];
        d1a = fmaf(mv.x, kv.x, d1a); d1b = fmaf(mv.y, kv.y, d1b);
        d1a = fmaf(mv.z, kv.z, d1a); d1b = fmaf(mv.w, kv.w, d1b);
      }
      float d0 = d0a + d0b, d1 = d1a + d1b;
      float sim0 = fminf(beta * d0 / (sqrtf(n2_0) * kn + kEPS), 80.f);
      float sim1 = fminf(beta * d1 / (sqrtf(n2_1) * kn + kEPS), 80.f);
      e0W = fexp(sim0); e1W = fexp(sim1);
      sm.E[tid] = e0W; sm.E[tid + NT] = e1W;
      sm.WP[tid] = wp0; sm.WP[tid + NT] = wp1;
      float sv = wsum(e0W + e1W);
      if (lane == 0) sm.red[0][wid] = sv;
    }
    __syncthreads();                                               // B4

    // ==== SEG 5: write-head addressing, part 2 (norm + shift + sharpen)
    {
      float gsum = 0.f;
      #pragma unroll
      for (int i = 0; i < NW; ++i) gsum += sm.red[0][i];
      float inv = __fdividef(1.f, gsum);
      float wg0 = fmaf(gW, fmaf(e0W, inv, -wp0), wp0);
      float wg1 = fmaf(gW, fmaf(e1W, inv, -wp1), wp1);
      int np = (tid + 1) & (kN - 1), nm = (tid + kN - 1) & (kN - 1);
      float wgp = fmaf(gW, fmaf(sm.E[np], inv, -sm.WP[np]), sm.WP[np]);
      float wgm = fmaf(gW, fmaf(sm.E[nm], inv, -sm.WP[nm]), sm.WP[nm]);
      float ws0 = s0W * wgp + s1W * wg0 + s2W * wgm;
      int npb = (tid + NT + 1) & (kN - 1), nmb = (tid + NT - 1) & (kN - 1);
      float wgpb = fmaf(gW, fmaf(sm.E[npb], inv, -sm.WP[npb]), sm.WP[npb]);
      float wgmb = fmaf(gW, fmaf(sm.E[nmb], inv, -sm.WP[nmb]), sm.WP[nmb]);
      float ws1 = s0W * wgpb + s1W * wg1 + s2W * wgmb;
      p0W = fexp(gammaW * __logf(ws0 + kEPS));
      p1W = fexp(gammaW * __logf(ws1 + kEPS));
      float pv = wsum(p0W + p1W);
      if (lane == 0) sm.red[1][wid] = pv;
    }
    __syncthreads();                                               // B5
    {
      float psum = 0.f;
      #pragma unroll
      for (int i = 0; i < NW; ++i) psum += sm.red[1][i];
      float ipn = __fdividef(1.f, psum);
      ww0 = p0W * ipn; ww1 = p1W * ipn;
    }

    // ==== SEG 6: memory update (+ read dot + norms) + read-head part 1
    float gR, s0R, s1R, s2R, gammaR;
    float e0R, e1R, p0R, p1R;
    float dr0 = 0.f, dr1 = 0.f, nn0 = 0.f, nn1 = 0.f;
    {
      #pragma unroll
      for (int bq = 0; bq < 16; ++bq) {
        float4 ev = *(const float4*)&sm.e[bq * 4];
        float4 av = *(const float4*)&sm.a[bq * 4];
        float4 kv = *(const float4*)&sm.kr[bq * 4];
        {
          float m = fmaf(ww0, fmaf(-ev.x, M0[bq * 4], av.x), M0[bq * 4]);
          M0[bq * 4] = m; dr0 = fmaf(m, kv.x, dr0); nn0 = fmaf(m, m, nn0);
        }
        {
          float m = fmaf(ww0, fmaf(-ev.y, M0[bq * 4 + 1], av.y), M0[bq * 4 + 1]);
          M0[bq * 4 + 1] = m; dr0 = fmaf(m, kv.y, dr0); nn0 = fmaf(m, m, nn0);
        }
        {
          float m = fmaf(ww0, fmaf(-ev.z, M0[bq * 4 + 2], av.z), M0[bq * 4 + 2]);
          M0[bq * 4 + 2] = m; dr0 = fmaf(m, kv.z, dr0); nn0 = fmaf(m, m, nn0);
        }
        {
          float m = fmaf(ww0, fmaf(-ev.w, M0[bq * 4 + 3], av.w), M0[bq * 4 + 3]);
          M0[bq * 4 + 3] = m; dr0 = fmaf(m, kv.w, dr0); nn0 = fmaf(m, m, nn0);
        }
        int fi = m1idx(bq, tid);
        float4 mv = *(const float4*)&sm.M1s[fi];
        float4 nm;
        nm.x = fmaf(ww1, fmaf(-ev.x, mv.x, av.x), mv.x);
        dr1 = fmaf(nm.x, kv.x, dr1); nn1 = fmaf(nm.x, nm.x, nn1);
        nm.y = fmaf(ww1, fmaf(-ev.y, mv.y, av.y), mv.y);
        dr1 = fmaf(nm.y, kv.y, dr1); nn1 = fmaf(nm.y, nm.y, nn1);
        nm.z = fmaf(ww1, fmaf(-ev.z, mv.z, av.z), mv.z);
        dr1 = fmaf(nm.z, kv.z, dr1); nn1 = fmaf(nm.z, nm.z, nn1);
        nm.w = fmaf(ww1, fmaf(-ev.w, mv.w, av.w), mv.w);
        dr1 = fmaf(nm.w, kv.w, dr1); nn1 = fmaf(nm.w, nm.w, nn1);
        *(float4*)&sm.M1s[fi] = nm;
      }
      float beta = softplusf_(sm.partA[kHW + 64] + sm.brS[64]);
      gR = sigmoidf_(sm.partA[kHW + 65] + sm.brS[65]);
      gammaR = 1.f + softplusf_(sm.partA[kHW + 69] + sm.brS[69]);
      float a0 = sm.partA[kHW + 66] + sm.brS[66];
      float a1 = sm.partA[kHW + 67] + sm.brS[67];
      float a2 = sm.partA[kHW + 68] + sm.brS[68];
      float mx = fmaxf(a0, fmaxf(a1, a2));
      float ex0 = fexp(a0 - mx), ex1 = fexp(a1 - mx), ex2 = fexp(a2 - mx);
      float dd = __fdividef(1.f, ex0 + ex1 + ex2);
      s0R = ex0 * dd; s1R = ex1 * dd; s2R = ex2 * dd;
      float kn = sm.scal[14];
      float sim0 = fminf(beta * dr0 / (sqrtf(nn0) * kn + kEPS), 80.f);
      float sim1 = fminf(beta * dr1 / (sqrtf(nn1) * kn + kEPS), 80.f);
      e0R = fexp(sim0); e1R = fexp(sim1);
      sm.E[tid] = e0R; sm.E[tid + NT] = e1R;
      sm.WP[tid] = ww0; sm.WP[tid + NT] = ww1;
      float sv = wsum(e0R + e1R);
      if (lane == 0) sm.red[0][wid] = sv;
    }
    __syncthreads();                                               // B6

    // ==== SEG 7: read-head part 2 + butterfly on UNNORMALIZED p
    {
      float gsum = 0.f;
      #pragma unroll
      for (int i = 0; i < NW; ++i) gsum += sm.red[0][i];
      float inv = __fdividef(1.f, gsum);
      float wg0 = fmaf(gR, fmaf(e0R, inv, -ww0), ww0);
      float wg1 = fmaf(gR, fmaf(e1R, inv, -ww1), ww1);
      int np = (tid + 1) & (kN - 1), nm = (tid + kN - 1) & (kN - 1);
      float wgp = fmaf(gR, fmaf(sm.E[np], inv, -sm.WP[np]), sm.WP[np]);
      float wgm = fmaf(gR, fmaf(sm.E[nm], inv, -sm.WP[nm]), sm.WP[nm]);
      float ws0 = s0R * wgp + s1R * wg0 + s2R * wgm;
      int npb = (tid + NT + 1) & (kN - 1), nmb = (tid + NT - 1) & (kN - 1);
      float wgpb = fmaf(gR, fmaf(sm.E[npb], inv, -sm.WP[npb]), sm.WP[npb]);
      float wgmb = fmaf(gR, fmaf(sm.E[nmb], inv, -sm.WP[nmb]), sm.WP[nmb]);
      float ws1 = s0R * wgpb + s1R * wg1 + s2R * wgmb;
      p0R = fexp(gammaR * __logf(ws0 + kEPS));
      p1R = fexp(gammaR * __logf(ws1 + kEPS));
      float pv = wsum(p0R + p1R);
      if (lane == 0) sm.red[1][wid] = pv;
      // butterfly pass A: columns 0..31, weights p0R/p1R (unnormalized)
      {
        float cur[16];
        const int b0 = lane & 1;
        #pragma unroll
        for (int qq = 0; qq < 8; ++qq) {
          float4 mv = *(const float4*)&sm.M1s[m1idx(qq, tid)];
          float v0 = fmaf(p0R, M0[4 * qq],     p1R * mv.x);
          float v1 = fmaf(p0R, M0[4 * qq + 1], p1R * mv.y);
          float keep = b0 ? v1 : v0, send = b0 ? v0 : v1;
          cur[2 * qq] = keep + __shfl_xor(send, 1);
          float v2 = fmaf(p0R, M0[4 * qq + 2], p1R * mv.z);
          float v3 = fmaf(p0R, M0[4 * qq + 3], p1R * mv.w);
          keep = b0 ? v3 : v2; send = b0 ? v2 : v3;
          cur[2 * qq + 1] = keep + __shfl_xor(send, 1);
        }
        #pragma unroll
        for (int st = 1; st < 5; ++st) {
          const int d = 1 << st;
          const int bb = (lane >> st) & 1;
          #pragma unroll
          for (int q = 0; q < (16 >> st); ++q) {
            float x0 = cur[2 * q], x1 = cur[2 * q + 1];
            float keep = bb ? x1 : x0, send = bb ? x0 : x1;
            cur[q] = keep + __shfl_xor(send, d);
          }
        }
        float tot = cur[0] + __shfl_xor(cur[0], 32);
        if (lane < 32) sm.partA[768 + wid * 64 + lane] = tot;
      }
      // butterfly pass B: columns 32..63
      {
        float cur[16];
        const int b0 = lane & 1;
        #pragma unroll
        for (int qq = 0; qq < 8; ++qq) {
          float4 mv = *(const float4*)&sm.M1s[m1idx(8 + qq, tid)];
          float v0 = fmaf(p0R, M0[32 + 4 * qq],     p1R * mv.x);
          float v1 = fmaf(p0R, M0[32 + 4 * qq + 1], p1R * mv.y);
          float keep = b0 ? v1 : v0, send = b0 ? v0 : v1;
          cur[2 * qq] = keep + __shfl_xor(send, 1);
          float v2 = fmaf(p0R, M0[32 + 4 * qq + 2], p1R * mv.z);
          float v3 = fmaf(p0R, M0[32 + 4 * qq + 3], p1R * mv.w);
          keep = b0 ? v3 : v2; send = b0 ? v2 : v3;
          cur[2 * qq + 1] = keep + __shfl_xor(send, 1);
        }
        #pragma unroll
        for (int st = 1; st < 5; ++st) {
          const int d = 1 << st;
          const int bb = (lane >> st) & 1;
          #pragma unroll
          for (int q = 0; q < (16 >> st); ++q) {
            float x0 = cur[2 * q], x1 = cur[2 * q + 1];
            float keep = bb ? x1 : x0, send = bb ? x0 : x1;
            cur[q] = keep + __shfl_xor(send, d);
          }
        }
        float tot = cur[0] + __shfl_xor(cur[0], 32);
        if (lane < 32) sm.partA[768 + wid * 64 + 32 + lane] = tot;
      }
    }
    __syncthreads();                                               // B7

    // ==== SEG 8: psum -> ipn; carry state; r reduce with ipn scaling
    {
      float psum = 0.f;
      #pragma unroll
      for (int i = 0; i < NW; ++i) psum += sm.red[1][i];
      float ipn = __fdividef(1.f, psum);
      wp0 = p0R * ipn; wp1 = p1R * ipn;      // carry normalized read weights
      n2_0 = nn0; n2_1 = nn1;
      if (tid < kMV) {
        float s = sm.partA[768 + tid];
        #pragma unroll
        for (int w = 1; w < NW; ++w) s += sm.partA[768 + w * 64 + tid];
        sm.r[tid] = s * ipn;
      }
    }
    __syncthreads();                                               // B8
  }

  // ==== epilogue: output for t = kT-1 (outc dots + r are intact)
  if (tid >= 256 && tid < 320) {
    const int j = tid - 256;
    float s = sm.bfS[j] + sm.partA[512 + j];
    if constexpr (MODE >= 1) {
      s += dot64(pk + kPWfT + j * (kC + kMV) + kC, sm.r);
    } else {
      for (int i = 0; i < kMV; ++i)
        s = fmaf(sm.r[i], ldf(Wf, (kC + i) * kOUT + j), s);
    }
    stf(out, ((size_t)b * kT + (kT - 1)) * kOUT + j, sigmoidf_(s));
  }
}

template <typename TD, int WANT, int MODE>
static void launch_variant(void* const* d_in, void* d_out, const int* flag,
                           const float* pk, const float* cpre, hipStream_t stream) {
  ntm_fused<TD, WANT, MODE><<<dim3(kB), dim3(NT), 0, stream>>>(
      (const TD*)d_in[0], (const TD*)d_in[1], (const TD*)d_in[2],
      (const TD*)d_in[3], (const TD*)d_in[4], (const TD*)d_in[5],
      (const TD*)d_in[6], (const TD*)d_in[7], (const TD*)d_in[8],
      (const TD*)d_in[9], (const TD*)d_in[10], (const TD*)d_in[11],
      pk, cpre, (TD*)d_out, flag);
}

extern "C" void kernel_launch(void* const* d_in, const int* in_sizes, int n_in,
                              void* d_out, int out_size, void* d_ws, size_t ws_size,
                              hipStream_t stream) {
  (void)in_sizes; (void)n_in; (void)out_size;
  int* flag = (int*)d_ws;
  detect_dtype<<<dim3(1), dim3(64), 0, stream>>>(d_in[10], flag);
  if (ws_size >= kWsPack) {
    float* pk = (float*)((char*)d_ws + 256);
    repack_w<__hip_bfloat16, 1><<<dim3(256), dim3(256), 0, stream>>>(
        (const __hip_bfloat16*)d_in[1], (const __hip_bfloat16*)d_in[5],
        (const __hip_bfloat16*)d_in[3], (const __hip_bfloat16*)d_in[7],
        pk, flag);
    repack_w<float, 0><<<dim3(256), dim3(256), 0, stream>>>(
        (const float*)d_in[1], (const float*)d_in[5],
        (const float*)d_in[3], (const float*)d_in[7],
        pk, flag);
    if (ws_size >= kWsFull) {
      float* cpre = (float*)((char*)d_ws + kWsPack);
      cpre_kernel<__hip_bfloat16, 1><<<dim3(kB * kT), dim3(kC), 0, stream>>>(
          (const __hip_bfloat16*)d_in[0], (const __hip_bfloat16*)d_in[2],
          pk, cpre, flag);
      cpre_kernel<float, 0><<<dim3(kB * kT), dim3(kC), 0, stream>>>(
          (const float*)d_in[0], (const float*)d_in[2],
          pk, cpre, flag);
      launch_variant<__hip_bfloat16, 1, 2>(d_in, d_out, flag, pk, cpre, stream);
      launch_variant<float, 0, 2>(d_in, d_out, flag, pk, cpre, stream);
    } else {
      launch_variant<__hip_bfloat16, 1, 1>(d_in, d_out, flag, pk, nullptr, stream);
      launch_variant<float, 0, 1>(d_in, d_out, flag, pk, nullptr, stream);
    }
  } else {
    launch_variant<__hip_bfloat16, 1, 0>(d_in, d_out, flag, nullptr, nullptr, stream);
    launch_variant<float, 0, 0>(d_in, d_out, flag, nullptr, nullptr, stream);
  }
}